// Round 2
// baseline (1253.857 us; speedup 1.0000x reference)
//
#include <hip/hip_runtime.h>
#include <math.h>

#define DIM   512
#define HID   64
#define NB    4
#define NS    8192
#define NPROJ 1536
#define FFT_N 8192
#define FFT_T 256
#define MTOT  (NB*NS)

// ---------------------------------------------------------------- utilities
__device__ __forceinline__ float2 cmulf(float2 a, float2 b) {
    return make_float2(a.x*b.x - a.y*b.y, a.x*b.y + a.y*b.x);
}
__device__ __forceinline__ float gelu_exact(float x) {
    return 0.5f * x * (1.0f + erff(x * 0.70710678118654752f));
}

// ---------------------------------------------------------------- filter MLP
__global__ void filter_mlp_kernel(const float* __restrict__ w1, const float* __restrict__ b1,
                                  const float* __restrict__ w2, const float* __restrict__ b2,
                                  const float* __restrict__ w3, const float* __restrict__ b3,
                                  float* __restrict__ filt) {
    __shared__ float h1[HID];
    __shared__ float h2[HID];
    const int s = blockIdx.x;
    const int t = threadIdx.x;          // 64 threads
    const float pos = (float)s / (float)(NS - 1);
    h1[t] = gelu_exact(pos * w1[t] + b1[t]);
    __syncthreads();
    float acc = b2[t];
    #pragma unroll 8
    for (int j = 0; j < HID; ++j) acc += h1[j] * w2[j*HID + t];
    h2[t] = gelu_exact(acc);
    __syncthreads();
    for (int d = t; d < DIM; d += HID) {
        float o = b3[d];
        #pragma unroll 8
        for (int j = 0; j < HID; ++j) o += h2[j] * w3[j*DIM + d];
        filt[(size_t)s*DIM + d] = o;
    }
}

// ---------------------------------------------------------------- FFT pieces
// Forward: DIF (Gentleman-Sande), natural input -> bit-reversed output.
__device__ void fft_dif_forward(float2* X) {
    const float TWO_PI = 6.28318530717958647692f;
    for (int lh = 12; lh >= 0; --lh) {
        const int half = 1 << lh;
        const float step = -TWO_PI / (float)(half << 1);
        for (int idx = threadIdx.x; idx < FFT_N/2; idx += FFT_T) {
            const int g = idx >> lh;
            const int k = idx & (half - 1);
            const int i0 = (g << (lh + 1)) + k;
            const int i1 = i0 + half;
            float2 a = X[i0], b = X[i1];
            float sv, cv;
            __sincosf(step * (float)k, &sv, &cv);
            float2 t = make_float2(a.x - b.x, a.y - b.y);
            X[i0] = make_float2(a.x + b.x, a.y + b.y);
            X[i1] = cmulf(t, make_float2(cv, sv));
        }
        __syncthreads();
    }
}
// Inverse: DIT (Cooley-Tukey), bit-reversed input -> natural output (unscaled).
__device__ void fft_dit_inverse(float2* X) {
    const float TWO_PI = 6.28318530717958647692f;
    for (int lh = 0; lh <= 12; ++lh) {
        const int half = 1 << lh;
        const float step = TWO_PI / (float)(half << 1);
        for (int idx = threadIdx.x; idx < FFT_N/2; idx += FFT_T) {
            const int g = idx >> lh;
            const int k = idx & (half - 1);
            const int i0 = (g << (lh + 1)) + k;
            const int i1 = i0 + half;
            float sv, cv;
            __sincosf(step * (float)k, &sv, &cv);
            float2 a = X[i0];
            float2 b = cmulf(X[i1], make_float2(cv, sv));
            X[i0] = make_float2(a.x + b.x, a.y + b.y);
            X[i1] = make_float2(a.x - b.x, a.y - b.y);
        }
        __syncthreads();
    }
}

// F_br[d][j] = DIF FFT of filt[:,d], stored bit-reversed. One block per d.
__global__ void fft_filt_kernel(const float* __restrict__ filt, float2* __restrict__ Fbr) {
    extern __shared__ float2 X[];
    const int d = blockIdx.x;
    for (int s = threadIdx.x; s < FFT_N; s += FFT_T)
        X[s] = make_float2(filt[(size_t)s*DIM + d], 0.0f);
    __syncthreads();
    fft_dif_forward(X);
    for (int j = threadIdx.x; j < FFT_N; j += FFT_T)
        Fbr[(size_t)d*FFT_N + j] = X[j];
}

// In-place circular conv per channel row of uT: u -> Re(IFFT(FFT(u).*F))/N.
__global__ void fft_conv_kernel(float* __restrict__ uT, const float2* __restrict__ Fbr) {
    extern __shared__ float2 X[];
    const int ch = blockIdx.x;            // b*DIM + d
    const int d = ch & (DIM - 1);
    float* u = uT + (size_t)ch * FFT_N;
    for (int s = threadIdx.x; s < FFT_N; s += FFT_T)
        X[s] = make_float2(u[s], 0.0f);
    __syncthreads();
    fft_dif_forward(X);
    for (int j = threadIdx.x; j < FFT_N; j += FFT_T)
        X[j] = cmulf(X[j], Fbr[(size_t)d*FFT_N + j]);
    __syncthreads();
    fft_dit_inverse(X);
    const float scale = 1.0f / (float)FFT_N;
    for (int s = threadIdx.x; s < FFT_N; s += FFT_T)
        u[s] = X[s].x * scale;
}

// ------------------------------------------------- depthwise conv + transpose
// reads u (B,S,D) stride DIM; writes uT (B,D,S) with k=3 pad=1 conv + bias.
__global__ void conv_transpose_kernel(const float* __restrict__ u,
                                      const float* __restrict__ conv_w,
                                      const float* __restrict__ conv_b,
                                      float* __restrict__ uT) {
    __shared__ float tile[66][65];
    const int bid = blockIdx.x;                 // b * (S/64) * (D/64)
    const int dt = bid & 7;
    const int st = (bid >> 3) & 127;
    const int b  = bid >> 10;
    const int d0 = dt * 64, s0 = st * 64;
    const int c  = threadIdx.x & 63;
    const int r0 = threadIdx.x >> 6;
    for (int r = r0; r < 66; r += 4) {
        const int s = s0 + r - 1;
        float v = 0.0f;
        if (s >= 0 && s < NS)
            v = u[((size_t)(b*NS + s))*DIM + d0 + c];
        tile[r][c] = v;
    }
    __syncthreads();
    const int sx = c;
    for (int dy = r0; dy < 64; dy += 4) {
        const int d = d0 + dy;
        const float w0 = conv_w[d*3+0], w1 = conv_w[d*3+1], w2 = conv_w[d*3+2];
        const float val = tile[sx][dy]*w0 + tile[sx+1][dy]*w1 + tile[sx+2][dy]*w2 + conv_b[d];
        uT[((size_t)(b*DIM + d))*NS + s0 + sx] = val;
    }
}

// ---------------------------------------------------------------- v * sigmoid(z)
__global__ void vz_kernel(float* __restrict__ v, const float* __restrict__ z) {
    const size_t i = (size_t)blockIdx.x * blockDim.x + threadIdx.x;
    float4 vv = reinterpret_cast<float4*>(v)[i];
    const float4 zz = reinterpret_cast<const float4*>(z)[i];
    vv.x *= 1.0f / (1.0f + __expf(-zz.x));
    vv.y *= 1.0f / (1.0f + __expf(-zz.y));
    vv.z *= 1.0f / (1.0f + __expf(-zz.z));
    vv.w *= 1.0f / (1.0f + __expf(-zz.w));
    reinterpret_cast<float4*>(v)[i] = vv;
}

// ---------------------------------------------------------------- gating
// vg (B,S,D) *= y read transposed from yT (B,D,S).
__global__ void gate_kernel(float* __restrict__ vg, const float* __restrict__ yT) {
    __shared__ float tile[64][65];
    const int bid = blockIdx.x;
    const int dt = bid & 7;
    const int st = (bid >> 3) & 127;
    const int b  = bid >> 10;
    const int d0 = dt * 64, s0 = st * 64;
    const int c  = threadIdx.x & 63;
    const int r0 = threadIdx.x >> 6;
    for (int dy = r0; dy < 64; dy += 4)
        tile[dy][c] = yT[((size_t)(b*DIM + d0 + dy))*NS + s0 + c];
    __syncthreads();
    for (int r = r0; r < 64; r += 4) {
        const int s = s0 + r;
        vg[((size_t)(b*NS + s))*DIM + d0 + c] *= tile[c][r];
    }
}

// ---------------------------------------------------------------- fp32 GEMM
// C[M,N](ldc) = A[M,K](lda) @ Bm[K,N](ldb) + bias.  128x128 tile, 8x8 micro.
#define GBM 128
#define GBN 128
#define GBK 8
__global__ __launch_bounds__(256)
void sgemm_bias_kernel(const float* __restrict__ A, int lda,
                       const float* __restrict__ Bm, int ldb,
                       const float* __restrict__ bias,
                       float* __restrict__ C, int ldc,
                       int M, int N, int K) {
    __shared__ float As[GBK][GBM + 4];
    __shared__ float Bs[GBK][GBN + 4];
    const int tid = threadIdx.x;
    const int tx = tid & 15, ty = tid >> 4;
    const int m0 = blockIdx.y * GBM, n0 = blockIdx.x * GBN;
    const int arow = tid >> 1, ak4 = (tid & 1) * 4;
    const int bkrow = tid >> 5, bcol4 = (tid & 31) * 4;
    float acc[8][8] = {};
    for (int k0 = 0; k0 < K; k0 += GBK) {
        const float4 a4 = *reinterpret_cast<const float4*>(&A[(size_t)(m0 + arow)*lda + k0 + ak4]);
        const float4 b4 = *reinterpret_cast<const float4*>(&Bm[(size_t)(k0 + bkrow)*ldb + n0 + bcol4]);
        __syncthreads();
        As[ak4+0][arow] = a4.x; As[ak4+1][arow] = a4.y;
        As[ak4+2][arow] = a4.z; As[ak4+3][arow] = a4.w;
        *reinterpret_cast<float4*>(&Bs[bkrow][bcol4]) = b4;
        __syncthreads();
        #pragma unroll
        for (int kk = 0; kk < GBK; ++kk) {
            float a[8], bb[8];
            #pragma unroll
            for (int i = 0; i < 8; ++i) a[i] = As[kk][ty*8 + i];
            #pragma unroll
            for (int j = 0; j < 8; ++j) bb[j] = Bs[kk][tx*8 + j];
            #pragma unroll
            for (int i = 0; i < 8; ++i)
                #pragma unroll
                for (int j = 0; j < 8; ++j)
                    acc[i][j] = fmaf(a[i], bb[j], acc[i][j]);
        }
    }
    float bv[8];
    #pragma unroll
    for (int j = 0; j < 8; ++j) bv[j] = bias[n0 + tx*8 + j];
    #pragma unroll
    for (int i = 0; i < 8; ++i) {
        const size_t row = m0 + ty*8 + i;
        float4 o0 = make_float4(acc[i][0]+bv[0], acc[i][1]+bv[1], acc[i][2]+bv[2], acc[i][3]+bv[3]);
        float4 o1 = make_float4(acc[i][4]+bv[4], acc[i][5]+bv[5], acc[i][6]+bv[6], acc[i][7]+bv[7]);
        *reinterpret_cast<float4*>(&C[row*ldc + n0 + tx*8])     = o0;
        *reinterpret_cast<float4*>(&C[row*ldc + n0 + tx*8 + 4]) = o1;
    }
}

// ------------------------------------------- in-place out_proj GEMM (32 x 512)
// C (M,512) <- C @ Bm(512,512) + bias.  Each block owns 32 full rows, so all
// its global A reads complete (consumed into LDS before the last barrier)
// before any epilogue write; rows are block-private -> in-place safe.
#define G2M 32
__global__ __launch_bounds__(256)
void sgemm_inplace_kernel(float* __restrict__ C,
                          const float* __restrict__ Bm,
                          const float* __restrict__ bias) {
    __shared__ float As[8][G2M];
    __shared__ float Bs[8][DIM];
    const int tid = threadIdx.x;
    const int m0 = blockIdx.x * G2M;
    const int tx = tid & 63;           // col group (x8)
    const int ty = tid >> 6;           // row group (x8)
    const int ar = tid >> 3, ak = tid & 7;
    const int br = tid >> 5, bc4 = (tid & 31) * 4;
    float acc[8][8] = {};
    for (int k0 = 0; k0 < DIM; k0 += 8) {
        const float a = C[(size_t)(m0 + ar)*DIM + k0 + ak];
        float4 b0 = *reinterpret_cast<const float4*>(&Bm[(size_t)(k0 + br)*DIM + bc4]);
        float4 b1 = *reinterpret_cast<const float4*>(&Bm[(size_t)(k0 + br)*DIM + bc4 + 128]);
        float4 b2 = *reinterpret_cast<const float4*>(&Bm[(size_t)(k0 + br)*DIM + bc4 + 256]);
        float4 b3 = *reinterpret_cast<const float4*>(&Bm[(size_t)(k0 + br)*DIM + bc4 + 384]);
        __syncthreads();
        As[ak][ar] = a;
        *reinterpret_cast<float4*>(&Bs[br][bc4])       = b0;
        *reinterpret_cast<float4*>(&Bs[br][bc4 + 128]) = b1;
        *reinterpret_cast<float4*>(&Bs[br][bc4 + 256]) = b2;
        *reinterpret_cast<float4*>(&Bs[br][bc4 + 384]) = b3;
        __syncthreads();
        #pragma unroll
        for (int kk = 0; kk < 8; ++kk) {
            float a_[8], b_[8];
            #pragma unroll
            for (int i = 0; i < 8; ++i) a_[i] = As[kk][ty*8 + i];
            #pragma unroll
            for (int j = 0; j < 8; ++j) b_[j] = Bs[kk][tx*8 + j];
            #pragma unroll
            for (int i = 0; i < 8; ++i)
                #pragma unroll
                for (int j = 0; j < 8; ++j)
                    acc[i][j] = fmaf(a_[i], b_[j], acc[i][j]);
        }
    }
    float bv[8];
    #pragma unroll
    for (int j = 0; j < 8; ++j) bv[j] = bias[tx*8 + j];
    #pragma unroll
    for (int i = 0; i < 8; ++i) {
        const size_t row = m0 + ty*8 + i;
        float4 o0 = make_float4(acc[i][0]+bv[0], acc[i][1]+bv[1], acc[i][2]+bv[2], acc[i][3]+bv[3]);
        float4 o1 = make_float4(acc[i][4]+bv[4], acc[i][5]+bv[5], acc[i][6]+bv[6], acc[i][7]+bv[7]);
        *reinterpret_cast<float4*>(&C[row*DIM + tx*8])     = o0;
        *reinterpret_cast<float4*>(&C[row*DIM + tx*8 + 4]) = o1;
    }
}

// ---------------------------------------------------------------- launcher
extern "C" void kernel_launch(void* const* d_in, const int* in_sizes, int n_in,
                              void* d_out, int out_size, void* d_ws, size_t ws_size,
                              hipStream_t stream) {
    const float* x      = (const float*)d_in[0];
    const float* w1     = (const float*)d_in[1];
    const float* b1     = (const float*)d_in[2];
    const float* w2     = (const float*)d_in[3];
    const float* b2     = (const float*)d_in[4];
    const float* w3     = (const float*)d_in[5];
    const float* b3     = (const float*)d_in[6];
    const float* conv_w = (const float*)d_in[7];
    const float* conv_b = (const float*)d_in[8];
    const float* w_in   = (const float*)d_in[9];
    const float* b_in   = (const float*)d_in[10];
    const float* w_out  = (const float*)d_in[11];
    const float* b_out  = (const float*)d_in[12];
    float* out = (float*)d_out;                      // doubles as v/g scratch

    // workspace: Fbr 32MiB | U1 64MiB | Bbuf 64MiB  (filt aliases U1)
    const size_t NEED = 167772160ULL;
    if (ws_size < NEED) return;                      // graceful fail -> absmax, not crash
    char* ws = (char*)d_ws;
    float2* Fbr  = (float2*)(ws);
    float*  U1   = (float*) (ws + 33554432);
    float*  Bbuf = (float*) (ws + 100663296);
    float*  filt = U1;

    // 1. filter MLP -> filt (S, D)
    filter_mlp_kernel<<<NS, HID, 0, stream>>>(w1, b1, w2, b2, w3, b3, filt);
    // 2. filter spectrum (bit-reversed) -> Fbr
    fft_filt_kernel<<<DIM, FFT_T, FFT_N*sizeof(float2), stream>>>(filt, Fbr);
    // 3. v = x @ w_in[:,0:512] + b  -> d_out
    sgemm_bias_kernel<<<dim3(4, MTOT/GBM), 256, 0, stream>>>(
        x, DIM, w_in, NPROJ, b_in, out, DIM, MTOT, DIM, DIM);
    // 4. z = x @ w_in[:,1024:1536] + b -> Bbuf
    sgemm_bias_kernel<<<dim3(4, MTOT/GBM), 256, 0, stream>>>(
        x, DIM, w_in + 1024, NPROJ, b_in + 1024, Bbuf, DIM, MTOT, DIM, DIM);
    // 5. d_out = v * sigmoid(z)
    vz_kernel<<<(MTOT*DIM/4)/256, 256, 0, stream>>>(out, Bbuf);
    // 6. u = x @ w_in[:,512:1024] + b -> U1   (after filt consumed)
    sgemm_bias_kernel<<<dim3(4, MTOT/GBM), 256, 0, stream>>>(
        x, DIM, w_in + 512, NPROJ, b_in + 512, U1, DIM, MTOT, DIM, DIM);
    // 7. depthwise conv + transpose: U1 (B,S,D) -> Bbuf (B,D,S)
    conv_transpose_kernel<<<NB*(NS/64)*(DIM/64), 256, 0, stream>>>(U1, conv_w, conv_b, Bbuf);
    // 8. FFT circular conv, in-place on Bbuf rows
    fft_conv_kernel<<<NB*DIM, FFT_T, FFT_N*sizeof(float2), stream>>>(Bbuf, Fbr);
    // 9. d_out *= filtered (transposed read)
    gate_kernel<<<NB*(NS/64)*(DIM/64), 256, 0, stream>>>(out, Bbuf);
    // 10. out = g @ w_out + b_out, in-place on d_out
    sgemm_inplace_kernel<<<MTOT/G2M, 256, 0, stream>>>(out, w_out, b_out);
}

// Round 3
// 347.032 us; speedup vs baseline: 3.6131x; 3.6131x over previous
//
#include <hip/hip_runtime.h>
#include <math.h>

#define DIM   512
#define NB    4
#define NS    8192
#define FFT_N 8192
#define FT    512
#define MTOT  (NB*NS)

typedef __attribute__((ext_vector_type(8))) short bf16x8;
typedef __attribute__((ext_vector_type(4))) short short4v;
typedef __attribute__((ext_vector_type(8))) short short8v;
typedef __attribute__((ext_vector_type(4))) float f32x4;

// ---------------------------------------------------------------- helpers
__device__ __forceinline__ float bf2f(unsigned short u) {
    union { unsigned int i; float f; } v; v.i = ((unsigned int)u) << 16; return v.f;
}
__device__ __forceinline__ unsigned short f2bf(float f) {
    union { float f; unsigned int i; } v; v.f = f;
    unsigned int r = v.i + 0x7fffu + ((v.i >> 16) & 1u);
    return (unsigned short)(r >> 16);
}
__device__ __forceinline__ float2 cmulf(float2 a, float2 b) {
    return make_float2(a.x*b.x - a.y*b.y, a.x*b.y + a.y*b.x);
}
__device__ __forceinline__ float gelu_exact(float x) {
    return 0.5f * x * (1.0f + erff(x * 0.70710678118654752f));
}
__device__ __forceinline__ void gload16(const void* g, void* l) {
    __builtin_amdgcn_global_load_lds((const __attribute__((address_space(1))) void*)g,
                                     (__attribute__((address_space(3))) void*)l, 16, 0, 0);
}

// ---------------------------------------------------------------- filter MLP
__global__ void filter_mlp_kernel(const float* __restrict__ w1, const float* __restrict__ b1,
                                  const float* __restrict__ w2, const float* __restrict__ b2,
                                  const float* __restrict__ w3, const float* __restrict__ b3,
                                  float* __restrict__ filt) {
    __shared__ float h1[64];
    __shared__ float h2[64];
    const int s = blockIdx.x;
    const int t = threadIdx.x;          // 64 threads
    const float pos = (float)s / (float)(NS - 1);
    h1[t] = gelu_exact(pos * w1[t] + b1[t]);
    __syncthreads();
    float acc = b2[t];
    #pragma unroll 8
    for (int j = 0; j < 64; ++j) acc += h1[j] * w2[j*64 + t];
    h2[t] = gelu_exact(acc);
    __syncthreads();
    for (int d = t; d < DIM; d += 64) {
        float o = b3[d];
        #pragma unroll 8
        for (int j = 0; j < 64; ++j) o += h2[j] * w3[j*DIM + d];
        filt[(size_t)s*DIM + d] = o;
    }
}

// ------------------------------------------------- fp32 transpose (R,C)->(C,R)
__global__ void transpose_f32_kernel(const float* __restrict__ in, float* __restrict__ out,
                                     int R, int C) {
    __shared__ float tile[64][65];
    const int c0 = blockIdx.x * 64, r0 = blockIdx.y * 64;
    const int t = threadIdx.x;
    const int rr = t >> 4, c4 = (t & 15) * 4;
    #pragma unroll
    for (int p = 0; p < 4; ++p) {
        const int r = rr + p*16;
        float4 v = *(const float4*)&in[(size_t)(r0 + r)*C + c0 + c4];
        tile[r][c4+0]=v.x; tile[r][c4+1]=v.y; tile[r][c4+2]=v.z; tile[r][c4+3]=v.w;
    }
    __syncthreads();
    const int cc = t >> 4, r4 = (t & 15) * 4;
    #pragma unroll
    for (int p = 0; p < 4; ++p) {
        const int c = cc + p*16;
        float4 o = make_float4(tile[r4+0][c], tile[r4+1][c], tile[r4+2][c], tile[r4+3][c]);
        *(float4*)&out[(size_t)(c0 + c)*R + r0 + r4] = o;
    }
}

// ------------------------------------------- cast+transpose (R,C)f32->(C,R)bf16
__global__ void castT_kernel(const float* __restrict__ in, unsigned short* __restrict__ outT,
                             int R, int C) {
    __shared__ float tile[64][65];
    const int c0 = blockIdx.x * 64, r0 = blockIdx.y * 64;
    const int t = threadIdx.x;
    const int rr = t >> 4, c4 = (t & 15) * 4;
    #pragma unroll
    for (int p = 0; p < 4; ++p) {
        const int r = rr + p*16;
        float4 v = *(const float4*)&in[(size_t)(r0 + r)*C + c0 + c4];
        tile[r][c4+0]=v.x; tile[r][c4+1]=v.y; tile[r][c4+2]=v.z; tile[r][c4+3]=v.w;
    }
    __syncthreads();
    const int cc = t >> 4, r4 = (t & 15) * 4;
    #pragma unroll
    for (int p = 0; p < 4; ++p) {
        const int c = cc + p*16;
        short4v o;
        o[0] = (short)f2bf(tile[r4+0][c]); o[1] = (short)f2bf(tile[r4+1][c]);
        o[2] = (short)f2bf(tile[r4+2][c]); o[3] = (short)f2bf(tile[r4+3][c]);
        *(short4v*)&outT[(size_t)(c0 + c)*R + r0 + r4] = o;
    }
}

// ---------------------------------------------------------------- cast x->bf16
__global__ void cast_x_kernel(const float* __restrict__ in, unsigned short* __restrict__ out) {
    const size_t i = ((size_t)blockIdx.x * 256 + threadIdx.x) * 8;
    float4 a = *(const float4*)&in[i];
    float4 b = *(const float4*)&in[i+4];
    short8v o;
    o[0]=(short)f2bf(a.x); o[1]=(short)f2bf(a.y); o[2]=(short)f2bf(a.z); o[3]=(short)f2bf(a.w);
    o[4]=(short)f2bf(b.x); o[5]=(short)f2bf(b.y); o[6]=(short)f2bf(b.z); o[7]=(short)f2bf(b.w);
    *(short8v*)&out[i] = o;
}

// ---------------------------------------------------------------- FFT pieces
__device__ void fft_dif_forward(float2* X) {
    const float TWO_PI = 6.28318530717958647692f;
    for (int lh = 12; lh >= 0; --lh) {
        const int half = 1 << lh;
        const float step = -TWO_PI / (float)(half << 1);
        for (int idx = threadIdx.x; idx < FFT_N/2; idx += FT) {
            const int g = idx >> lh;
            const int k = idx & (half - 1);
            const int i0 = (g << (lh + 1)) + k;
            const int i1 = i0 + half;
            float2 a = X[i0], b = X[i1];
            float sv, cv;
            __sincosf(step * (float)k, &sv, &cv);
            float2 t = make_float2(a.x - b.x, a.y - b.y);
            X[i0] = make_float2(a.x + b.x, a.y + b.y);
            X[i1] = cmulf(t, make_float2(cv, sv));
        }
        __syncthreads();
    }
}
__device__ void fft_dit_inverse(float2* X) {
    const float TWO_PI = 6.28318530717958647692f;
    for (int lh = 0; lh <= 12; ++lh) {
        const int half = 1 << lh;
        const float step = TWO_PI / (float)(half << 1);
        for (int idx = threadIdx.x; idx < FFT_N/2; idx += FT) {
            const int g = idx >> lh;
            const int k = idx & (half - 1);
            const int i0 = (g << (lh + 1)) + k;
            const int i1 = i0 + half;
            float sv, cv;
            __sincosf(step * (float)k, &sv, &cv);
            float2 a = X[i0];
            float2 b = cmulf(X[i1], make_float2(cv, sv));
            X[i0] = make_float2(a.x + b.x, a.y + b.y);
            X[i1] = make_float2(a.x - b.x, a.y - b.y);
        }
        __syncthreads();
    }
}

// filter spectrum, bit-reversed order; filtT (D, S) fp32 rows coalesced
__global__ __launch_bounds__(FT)
void fft_filt_kernel(const float* __restrict__ filtT, float2* __restrict__ Fbr) {
    extern __shared__ float2 X[];
    const int d = blockIdx.x;
    const float* f = filtT + (size_t)d * FFT_N;
    for (int i = threadIdx.x; i < FFT_N; i += FT)
        X[i] = make_float2(f[i], 0.0f);
    __syncthreads();
    fft_dif_forward(X);
    for (int i = threadIdx.x; i < FFT_N; i += FT)
        Fbr[(size_t)d*FFT_N + i] = X[i];
}

// packed pair conv: z = u[2p][d] + i*u[2p+1][d]; y = IFFT(FFT(z).*F); in-place bf16
__global__ __launch_bounds__(FT)
void fft_conv_kernel(unsigned short* __restrict__ uT, const float2* __restrict__ Fbr) {
    extern __shared__ float2 X[];
    const int d = blockIdx.x & (DIM - 1);
    const int p = blockIdx.x >> 9;
    unsigned short* u1 = uT + (size_t)((2*p    )*DIM + d) * FFT_N;
    unsigned short* u2 = uT + (size_t)((2*p + 1)*DIM + d) * FFT_N;
    for (int i = threadIdx.x; i < FFT_N; i += FT)
        X[i] = make_float2(bf2f(u1[i]), bf2f(u2[i]));
    __syncthreads();
    fft_dif_forward(X);
    for (int j = threadIdx.x; j < FFT_N; j += FT)
        X[j] = cmulf(X[j], Fbr[(size_t)d*FFT_N + j]);
    __syncthreads();
    fft_dit_inverse(X);
    const float sc = 1.0f / (float)FFT_N;
    for (int i = threadIdx.x; i < FFT_N; i += FT) {
        u1[i] = f2bf(X[i].x * sc);
        u2[i] = f2bf(X[i].y * sc);
    }
}

// ------------------------------------------------- depthwise conv + transpose
// u (B,S,D) bf16 -> uT (B,D,S) bf16, k=3 pad=1 conv + bias (fp32 math)
__global__ void conv_transpose_kernel(const unsigned short* __restrict__ u,
                                      const float* __restrict__ conv_w,
                                      const float* __restrict__ conv_b,
                                      unsigned short* __restrict__ uT) {
    __shared__ float tile[66][65];
    const int bid = blockIdx.x;
    const int dt = bid & 7, st = (bid >> 3) & 127, b = bid >> 10;
    const int d0 = dt*64, s0 = st*64;
    const int t = threadIdx.x;
    const int rr = t >> 4, c4 = (t & 15) * 4;
    for (int r = rr; r < 66; r += 16) {
        const int s = s0 + r - 1;
        float v0=0.f, v1=0.f, v2=0.f, v3=0.f;
        if (s >= 0 && s < NS) {
            short4v xv = *(const short4v*)&u[((size_t)(b*NS + s))*DIM + d0 + c4];
            v0=bf2f((unsigned short)xv[0]); v1=bf2f((unsigned short)xv[1]);
            v2=bf2f((unsigned short)xv[2]); v3=bf2f((unsigned short)xv[3]);
        }
        tile[r][c4]=v0; tile[r][c4+1]=v1; tile[r][c4+2]=v2; tile[r][c4+3]=v3;
    }
    __syncthreads();
    const int dl = t >> 4, s4 = (t & 15) * 4;
    #pragma unroll
    for (int p = 0; p < 4; ++p) {
        const int dc = dl + p*16;
        const int d = d0 + dc;
        const float w0 = conv_w[d*3], w1 = conv_w[d*3+1], w2 = conv_w[d*3+2];
        const float cb = conv_b[d];
        short4v o;
        #pragma unroll
        for (int j = 0; j < 4; ++j) {
            const int sx = s4 + j;
            const float val = tile[sx][dc]*w0 + tile[sx+1][dc]*w1 + tile[sx+2][dc]*w2 + cb;
            o[j] = (short)f2bf(val);
        }
        *(short4v*)&uT[((size_t)(b*DIM + d))*FFT_N + s0 + s4] = o;
    }
}

// ---------------------------------------------------------------- gating
// vg (B,S,D) bf16 *= y from yT (B,D,S) bf16 (in-place)
__global__ void gate_kernel(unsigned short* __restrict__ vg, const unsigned short* __restrict__ yT) {
    __shared__ float tile[64][65];
    const int bid = blockIdx.x;
    const int dt = bid & 7, st = (bid >> 3) & 127, b = bid >> 10;
    const int d0 = dt*64, s0 = st*64;
    const int t = threadIdx.x;
    const int dl = t >> 4, s4 = (t & 15) * 4;
    #pragma unroll
    for (int p = 0; p < 4; ++p) {
        const int d = dl + p*16;
        short4v y = *(const short4v*)&yT[((size_t)(b*DIM + d0 + d))*FFT_N + s0 + s4];
        tile[d][s4]  =bf2f((unsigned short)y[0]); tile[d][s4+1]=bf2f((unsigned short)y[1]);
        tile[d][s4+2]=bf2f((unsigned short)y[2]); tile[d][s4+3]=bf2f((unsigned short)y[3]);
    }
    __syncthreads();
    const int sl = t >> 4, d4 = (t & 15) * 4;
    #pragma unroll
    for (int p = 0; p < 4; ++p) {
        const int s = s0 + sl + p*16;
        unsigned short* pv = &vg[((size_t)(b*NS + s))*DIM + d0 + d4];
        short4v v = *(short4v*)pv;
        short4v o;
        #pragma unroll
        for (int j = 0; j < 4; ++j)
            o[j] = (short)f2bf(bf2f((unsigned short)v[j]) * tile[d4+j][sl + p*16]);
        *(short4v*)pv = o;
    }
}

// ---------------------------------------------------------------- bf16 GEMM
// C[M,N=512] = A[M,512]bf16 @ BT[N,512]bf16^T + bias
// MODE 0: Cb = bf16(val);  MODE 1: Cb = bf16(sigmoid(val)*bf2f(Cb)) in-place;
// MODE 2: Cf = val (fp32)
template<int MODE>
__global__ __launch_bounds__(256)
void gemm_bt_kernel(const unsigned short* __restrict__ A,
                    const unsigned short* __restrict__ BT,
                    const float* __restrict__ bias,
                    float* __restrict__ Cf,
                    unsigned short* __restrict__ Cb) {
    __shared__ unsigned short As[128*32];
    __shared__ unsigned short Bs[128*32];
    const int tid = threadIdx.x;
    const int wid = tid >> 6, lane = tid & 63;
    const int m0 = blockIdx.y * 128, n0 = blockIdx.x * 128;
    const int srow = wid*16 + (lane >> 2);
    const int scol = (lane & 3) * 8;
    const unsigned short* gA = A  + (size_t)(m0 + srow)*DIM + scol;
    const unsigned short* gB = BT + (size_t)(n0 + srow)*DIM + scol;
    unsigned short* lA = As + wid*512;
    unsigned short* lB = Bs + wid*512;
    const int wr = wid >> 1, wc = wid & 1;
    const int fr = lane & 15, fq = lane >> 4;
    f32x4 acc[4][4] = {};
    for (int k0 = 0; k0 < DIM; k0 += 32) {
        __syncthreads();
        gload16(gA + k0,                 lA);
        gload16(gA + k0 + (size_t)64*DIM, lA + 2048);
        gload16(gB + k0,                 lB);
        gload16(gB + k0 + (size_t)64*DIM, lB + 2048);
        __syncthreads();
        bf16x8 af[4], bfr[4];
        #pragma unroll
        for (int mi = 0; mi < 4; ++mi)
            af[mi] = *(const bf16x8*)&As[(wr*64 + mi*16 + fr)*32 + fq*8];
        #pragma unroll
        for (int ni = 0; ni < 4; ++ni)
            bfr[ni] = *(const bf16x8*)&Bs[(wc*64 + ni*16 + fr)*32 + fq*8];
        #pragma unroll
        for (int mi = 0; mi < 4; ++mi)
            #pragma unroll
            for (int ni = 0; ni < 4; ++ni)
                acc[mi][ni] = __builtin_amdgcn_mfma_f32_16x16x32_bf16(af[mi], bfr[ni], acc[mi][ni], 0, 0, 0);
    }
    #pragma unroll
    for (int ni = 0; ni < 4; ++ni) {
        const int c = n0 + wc*64 + ni*16 + fr;
        const float bv = bias[c];
        #pragma unroll
        for (int mi = 0; mi < 4; ++mi) {
            const int rbase = m0 + wr*64 + mi*16 + fq*4;
            #pragma unroll
            for (int j = 0; j < 4; ++j) {
                const size_t idx = (size_t)(rbase + j)*DIM + c;
                const float val = acc[mi][ni][j] + bv;
                if (MODE == 0) {
                    Cb[idx] = f2bf(val);
                } else if (MODE == 1) {
                    const float vold = bf2f(Cb[idx]);
                    const float sg = 1.0f / (1.0f + __expf(-val));
                    Cb[idx] = f2bf(vold * sg);
                } else {
                    Cf[idx] = val;
                }
            }
        }
    }
}

// ---------------------------------------------------------------- launcher
extern "C" void kernel_launch(void* const* d_in, const int* in_sizes, int n_in,
                              void* d_out, int out_size, void* d_ws, size_t ws_size,
                              hipStream_t stream) {
    const float* x      = (const float*)d_in[0];
    const float* w1     = (const float*)d_in[1];
    const float* b1     = (const float*)d_in[2];
    const float* w2     = (const float*)d_in[3];
    const float* b2     = (const float*)d_in[4];
    const float* w3     = (const float*)d_in[5];
    const float* b3     = (const float*)d_in[6];
    const float* conv_w = (const float*)d_in[7];
    const float* conv_b = (const float*)d_in[8];
    const float* w_in   = (const float*)d_in[9];
    const float* b_in   = (const float*)d_in[10];
    const float* w_out  = (const float*)d_in[11];
    const float* b_out  = (const float*)d_in[12];
    float* out = (float*)d_out;

    const size_t NEED = 167772160ULL;              // 160 MiB (known to fit)
    if (ws_size < NEED) return;
    char* ws = (char*)d_ws;
    float2*         Fbr    = (float2*)ws;                               // 32 MiB
    unsigned short* xb     = (unsigned short*)(ws + (size_t)( 32<<20)); // 32 MiB
    unsigned short* W2     = (unsigned short*)(ws + (size_t)( 64<<20)); // u / v / g
    unsigned short* W3     = (unsigned short*)(ws + (size_t)( 96<<20)); // filtT / uT
    char*           W4     = ws + (size_t)(128<<20);
    float*          filt   = (float*)W4;
    float*          filtT  = (float*)(ws + (size_t)(96<<20));
    unsigned short* w_inT  = (unsigned short*)W4;                       // after filt dead
    unsigned short* w_outT = (unsigned short*)(W4 + (size_t)(2<<20));

    // 1. implicit filter MLP -> filt (S, D) fp32
    filter_mlp_kernel<<<NS, 64, 0, stream>>>(w1, b1, w2, b2, w3, b3, filt);
    // 2. transpose filt -> filtT (D, S) fp32
    transpose_f32_kernel<<<dim3(DIM/64, NS/64), 256, 0, stream>>>(filt, filtT, NS, DIM);
    // 3. filter spectrum (bit-reversed) -> Fbr
    fft_filt_kernel<<<DIM, FT, FFT_N*sizeof(float2), stream>>>(filtT, Fbr);
    // 4. casts
    cast_x_kernel<<<(MTOT*DIM/8)/256, 256, 0, stream>>>(x, xb);
    castT_kernel<<<dim3(1536/64, DIM/64), 256, 0, stream>>>(w_in, w_inT, DIM, 1536);
    castT_kernel<<<dim3(DIM/64, DIM/64), 256, 0, stream>>>(w_out, w_outT, DIM, DIM);
    // 5. u = x @ w_in[:,512:1024] + b -> W2 (bf16)
    gemm_bt_kernel<0><<<dim3(4, MTOT/128), 256, 0, stream>>>(xb, w_inT + 512*DIM, b_in + 512, nullptr, W2);
    // 6. depthwise conv + transpose: W2 -> W3 (B,D,S)
    conv_transpose_kernel<<<NB*(NS/64)*(DIM/64), 256, 0, stream>>>(W2, conv_w, conv_b, W3);
    // 7. packed FFT circular conv, in-place on W3 rows
    fft_conv_kernel<<<(NB/2)*DIM, FT, FFT_N*sizeof(float2), stream>>>(W3, Fbr);
    // 8. v = x @ w_in[:,0:512] + b -> W2
    gemm_bt_kernel<0><<<dim3(4, MTOT/128), 256, 0, stream>>>(xb, w_inT, b_in, nullptr, W2);
    // 9. g0 = v * sigmoid(z), z-GEMM fused, in-place on W2
    gemm_bt_kernel<1><<<dim3(4, MTOT/128), 256, 0, stream>>>(xb, w_inT + 1024*DIM, b_in + 1024, nullptr, W2);
    // 10. g = g0 * y (transposed read of W3), in-place on W2
    gate_kernel<<<NB*(NS/64)*(DIM/64), 256, 0, stream>>>(W2, W3);
    // 11. out = g @ w_out + b_out -> d_out fp32
    gemm_bt_kernel<2><<<dim3(4, MTOT/128), 256, 0, stream>>>(W2, w_outT, b_out, out, nullptr);
}

// Round 5
// 320.326 us; speedup vs baseline: 3.9143x; 1.0834x over previous
//
#include <hip/hip_runtime.h>
#include <math.h>

#define DIM   512
#define NB    4
#define NS    8192
#define FFT_N 8192
#define FT    1024
#define MTOT  (NB*NS)

typedef __attribute__((ext_vector_type(8))) short bf16x8;
typedef __attribute__((ext_vector_type(4))) short short4v;
typedef __attribute__((ext_vector_type(8))) short short8v;
typedef __attribute__((ext_vector_type(4))) float f32x4;

// ---------------------------------------------------------------- helpers
__device__ __forceinline__ float bf2f(unsigned short u) {
    union { unsigned int i; float f; } v; v.i = ((unsigned int)u) << 16; return v.f;
}
__device__ __forceinline__ unsigned short f2bf(float f) {
    union { float f; unsigned int i; } v; v.f = f;
    unsigned int r = v.i + 0x7fffu + ((v.i >> 16) & 1u);
    return (unsigned short)(r >> 16);
}
__device__ __forceinline__ float2 cmulf(float2 a, float2 b) {
    return make_float2(a.x*b.x - a.y*b.y, a.x*b.y + a.y*b.x);
}
__device__ __forceinline__ float2 cadd(float2 a, float2 b) { return make_float2(a.x+b.x, a.y+b.y); }
__device__ __forceinline__ float2 csub(float2 a, float2 b) { return make_float2(a.x-b.x, a.y-b.y); }
__device__ __forceinline__ float gelu_exact(float x) {
    return 0.5f * x * (1.0f + erff(x * 0.70710678118654752f));
}
__device__ __forceinline__ void gload16(const void* g, void* l) {
    __builtin_amdgcn_global_load_lds((const __attribute__((address_space(1))) void*)g,
                                     (__attribute__((address_space(3))) void*)l, 16, 0, 0);
}

// ---------------------------------------------------------------- filter MLP
__global__ void filter_mlp_kernel(const float* __restrict__ w1, const float* __restrict__ b1,
                                  const float* __restrict__ w2, const float* __restrict__ b2,
                                  const float* __restrict__ w3, const float* __restrict__ b3,
                                  float* __restrict__ filt) {
    __shared__ float h1[64];
    __shared__ float h2[64];
    const int s = blockIdx.x;
    const int t = threadIdx.x;          // 64 threads
    const float pos = (float)s / (float)(NS - 1);
    h1[t] = gelu_exact(pos * w1[t] + b1[t]);
    __syncthreads();
    float acc = b2[t];
    #pragma unroll 8
    for (int j = 0; j < 64; ++j) acc += h1[j] * w2[j*64 + t];
    h2[t] = gelu_exact(acc);
    __syncthreads();
    for (int d = t; d < DIM; d += 64) {
        float o = b3[d];
        #pragma unroll 8
        for (int j = 0; j < 64; ++j) o += h2[j] * w3[j*DIM + d];
        filt[(size_t)s*DIM + d] = o;
    }
}

// ------------------------------------------------- fp32 transpose (R,C)->(C,R)
__global__ void transpose_f32_kernel(const float* __restrict__ in, float* __restrict__ out,
                                     int R, int C) {
    __shared__ float tile[64][65];
    const int c0 = blockIdx.x * 64, r0 = blockIdx.y * 64;
    const int t = threadIdx.x;
    const int rr = t >> 4, c4 = (t & 15) * 4;
    #pragma unroll
    for (int p = 0; p < 4; ++p) {
        const int r = rr + p*16;
        float4 v = *(const float4*)&in[(size_t)(r0 + r)*C + c0 + c4];
        tile[r][c4+0]=v.x; tile[r][c4+1]=v.y; tile[r][c4+2]=v.z; tile[r][c4+3]=v.w;
    }
    __syncthreads();
    const int cc = t >> 4, r4 = (t & 15) * 4;
    #pragma unroll
    for (int p = 0; p < 4; ++p) {
        const int c = cc + p*16;
        float4 o = make_float4(tile[r4+0][c], tile[r4+1][c], tile[r4+2][c], tile[r4+3][c]);
        *(float4*)&out[(size_t)(c0 + c)*R + r0 + r4] = o;
    }
}

// ------------------------------------------- cast+transpose (R,C)f32->(C,R)bf16
__global__ void castT_kernel(const float* __restrict__ in, unsigned short* __restrict__ outT,
                             int R, int C) {
    __shared__ float tile[64][65];
    const int c0 = blockIdx.x * 64, r0 = blockIdx.y * 64;
    const int t = threadIdx.x;
    const int rr = t >> 4, c4 = (t & 15) * 4;
    #pragma unroll
    for (int p = 0; p < 4; ++p) {
        const int r = rr + p*16;
        float4 v = *(const float4*)&in[(size_t)(r0 + r)*C + c0 + c4];
        tile[r][c4+0]=v.x; tile[r][c4+1]=v.y; tile[r][c4+2]=v.z; tile[r][c4+3]=v.w;
    }
    __syncthreads();
    const int cc = t >> 4, r4 = (t & 15) * 4;
    #pragma unroll
    for (int p = 0; p < 4; ++p) {
        const int c = cc + p*16;
        short4v o;
        o[0] = (short)f2bf(tile[r4+0][c]); o[1] = (short)f2bf(tile[r4+1][c]);
        o[2] = (short)f2bf(tile[r4+2][c]); o[3] = (short)f2bf(tile[r4+3][c]);
        *(short4v*)&outT[(size_t)(c0 + c)*R + r0 + r4] = o;
    }
}

// ---------------------------------------------------------------- cast x->bf16
__global__ void cast_x_kernel(const float* __restrict__ in, unsigned short* __restrict__ out) {
    const size_t i = ((size_t)blockIdx.x * 256 + threadIdx.x) * 8;
    float4 a = *(const float4*)&in[i];
    float4 b = *(const float4*)&in[i+4];
    short8v o;
    o[0]=(short)f2bf(a.x); o[1]=(short)f2bf(a.y); o[2]=(short)f2bf(a.z); o[3]=(short)f2bf(a.w);
    o[4]=(short)f2bf(b.x); o[5]=(short)f2bf(b.y); o[6]=(short)f2bf(b.z); o[7]=(short)f2bf(b.w);
    *(short8v*)&out[i] = o;
}

// ---------------------------------------------------------------- FFT pieces
// Radix-4 DIF forward stage: q = quarter, L = 4q, W = e^{-2pi i/L}
template<int LOGQ>
__device__ __forceinline__ void dif4_stage(float2* X) {
    const int q = 1 << LOGQ;
    const float step = -6.28318530717958647692f / (float)(4*q);
    #pragma unroll
    for (int it = 0; it < (FFT_N/4)/FT; ++it) {
        const int idx = threadIdx.x + it*FT;
        const int g = idx >> LOGQ, k = idx & (q-1);
        const int base = (g << (LOGQ+2)) + k;
        float2 a=X[base], b=X[base+q], c=X[base+2*q], d=X[base+3*q];
        float2 t0=cadd(a,c), t1=csub(a,c), t2=cadd(b,d), t3=csub(b,d);
        float2 y0=cadd(t0,t2), y2=csub(t0,t2);
        float2 y1=make_float2(t1.x+t3.y, t1.y-t3.x);   // t1 - i*t3
        float2 y3=make_float2(t1.x-t3.y, t1.y+t3.x);   // t1 + i*t3
        float sv, cv; __sincosf(step*(float)k, &sv, &cv);
        float2 w1=make_float2(cv, sv);
        float2 w2=cmulf(w1, w1);
        float2 w3=cmulf(w2, w1);
        X[base]     = y0;
        X[base+q]   = cmulf(y1, w1);
        X[base+2*q] = cmulf(y2, w2);
        X[base+3*q] = cmulf(y3, w3);
    }
    __syncthreads();
}

// Radix-4 DIT inverse stage (conjugate twiddles), exact inverse of dif4_stage
template<int LOGQ>
__device__ __forceinline__ void dit4_stage_inv(float2* X) {
    const int q = 1 << LOGQ;
    const float step = 6.28318530717958647692f / (float)(4*q);
    #pragma unroll
    for (int it = 0; it < (FFT_N/4)/FT; ++it) {
        const int idx = threadIdx.x + it*FT;
        const int g = idx >> LOGQ, k = idx & (q-1);
        const int base = (g << (LOGQ+2)) + k;
        float sv, cv; __sincosf(step*(float)k, &sv, &cv);
        float2 w1=make_float2(cv, sv);
        float2 w2=cmulf(w1, w1);
        float2 w3=cmulf(w2, w1);
        float2 u0=X[base];
        float2 u1=cmulf(X[base+q],   w1);
        float2 u2=cmulf(X[base+2*q], w2);
        float2 u3=cmulf(X[base+3*q], w3);
        float2 s02=cadd(u0,u2), d02=csub(u0,u2);
        float2 s13=cadd(u1,u3), d13=csub(u1,u3);
        X[base]     = cadd(s02, s13);
        X[base+2*q] = csub(s02, s13);
        X[base+q]   = make_float2(d02.x - d13.y, d02.y + d13.x);   // d02 + i*d13
        X[base+3*q] = make_float2(d02.x + d13.y, d02.y - d13.x);   // d02 - i*d13
    }
    __syncthreads();
}

// Register tail: size-8 DFT on 8 contiguous elements (radix-4 q=2 + radix-2)
__device__ __forceinline__ void reg_fwd(float2* E) {
    const float C = 0.70710678118654752f;
    {   // k=0: elems 0,2,4,6, twiddles = 1
        float2 t0=cadd(E[0],E[4]), t1=csub(E[0],E[4]);
        float2 t2=cadd(E[2],E[6]), t3=csub(E[2],E[6]);
        E[0]=cadd(t0,t2);
        E[4]=csub(t0,t2);
        E[2]=make_float2(t1.x+t3.y, t1.y-t3.x);
        E[6]=make_float2(t1.x-t3.y, t1.y+t3.x);
    }
    {   // k=1: elems 1,3,5,7; w1=(C,-C), w2=(0,-1), w3=(-C,-C)
        float2 t0=cadd(E[1],E[5]), t1=csub(E[1],E[5]);
        float2 t2=cadd(E[3],E[7]), t3=csub(E[3],E[7]);
        float2 y0=cadd(t0,t2), y2=csub(t0,t2);
        float2 y1=make_float2(t1.x+t3.y, t1.y-t3.x);
        float2 y3=make_float2(t1.x-t3.y, t1.y+t3.x);
        E[1]=y0;
        E[3]=make_float2(C*(y1.x+y1.y),  C*(y1.y-y1.x));   // y1*(C,-C)
        E[5]=make_float2(y2.y, -y2.x);                      // -i*y2
        E[7]=make_float2(C*(y3.y-y3.x), -C*(y3.x+y3.y));    // y3*(-C,-C)
    }
    #pragma unroll
    for (int j = 0; j < 8; j += 2) {
        float2 a=E[j], b=E[j+1];
        E[j]=cadd(a,b); E[j+1]=csub(a,b);
    }
}
__device__ __forceinline__ void reg_inv(float2* E) {
    const float C = 0.70710678118654752f;
    #pragma unroll
    for (int j = 0; j < 8; j += 2) {
        float2 a=E[j], b=E[j+1];
        E[j]=cadd(a,b); E[j+1]=csub(a,b);
    }
    {   // k=0
        float2 u0=E[0], u1=E[2], u2=E[4], u3=E[6];
        float2 s02=cadd(u0,u2), d02=csub(u0,u2);
        float2 s13=cadd(u1,u3), d13=csub(u1,u3);
        E[0]=cadd(s02,s13);
        E[4]=csub(s02,s13);
        E[2]=make_float2(d02.x - d13.y, d02.y + d13.x);
        E[6]=make_float2(d02.x + d13.y, d02.y - d13.x);
    }
    {   // k=1: conj twiddles (C,C), (0,1), (-C,C)
        float2 z1=E[3], z2=E[5], z3=E[7];
        float2 u0=E[1];
        float2 u1=make_float2(C*(z1.x - z1.y), C*(z1.x + z1.y));
        float2 u2=make_float2(-z2.y, z2.x);
        float2 u3=make_float2(-C*(z3.x + z3.y), C*(z3.x - z3.y));
        float2 s02=cadd(u0,u2), d02=csub(u0,u2);
        float2 s13=cadd(u1,u3), d13=csub(u1,u3);
        E[1]=cadd(s02,s13);
        E[5]=csub(s02,s13);
        E[3]=make_float2(d02.x - d13.y, d02.y + d13.x);
        E[7]=make_float2(d02.x + d13.y, d02.y - d13.x);
    }
}

__device__ __forceinline__ void load8(const float2* X, int t, float2* E) {
    const float4* b = (const float4*)(X + 8*t);
    #pragma unroll
    for (int p = 0; p < 4; ++p) {
        float4 v = b[p];
        E[2*p]   = make_float2(v.x, v.y);
        E[2*p+1] = make_float2(v.z, v.w);
    }
}
__device__ __forceinline__ void store8(float2* X, int t, const float2* E) {
    float4* b = (float4*)(X + 8*t);
    #pragma unroll
    for (int p = 0; p < 4; ++p)
        b[p] = make_float4(E[2*p].x, E[2*p].y, E[2*p+1].x, E[2*p+1].y);
}

// filter spectrum (permuted order P); filtT (D, S) fp32 rows
__global__ __launch_bounds__(FT)
void fft_filt_kernel(const float* __restrict__ filtT, float2* __restrict__ Fbr) {
    extern __shared__ float4 Xraw[];
    float2* X = (float2*)Xraw;
    const int dd = blockIdx.x;
    const int t = threadIdx.x;
    const float* f = filtT + (size_t)dd * FFT_N;
    {
        float4 a = *(const float4*)(f + 8*t);
        float4 b = *(const float4*)(f + 8*t + 4);
        float2 E[8];
        E[0]=make_float2(a.x,0.f); E[1]=make_float2(a.y,0.f);
        E[2]=make_float2(a.z,0.f); E[3]=make_float2(a.w,0.f);
        E[4]=make_float2(b.x,0.f); E[5]=make_float2(b.y,0.f);
        E[6]=make_float2(b.z,0.f); E[7]=make_float2(b.w,0.f);
        store8(X, t, E);
    }
    __syncthreads();
    dif4_stage<11>(X);
    dif4_stage<9>(X);
    dif4_stage<7>(X);
    dif4_stage<5>(X);
    dif4_stage<3>(X);
    {
        float2 E[8];
        load8(X, t, E);
        reg_fwd(E);
        float2* o = Fbr + (size_t)dd*FFT_N + 8*t;
        #pragma unroll
        for (int j = 0; j < 8; ++j) o[j] = E[j];
    }
}

// packed-pair circular conv, in-place bf16: rows (2p,d) and (2p+1,d) of uT
__global__ __launch_bounds__(FT)
void fft_conv_kernel(unsigned short* __restrict__ uT, const float2* __restrict__ Fbr) {
    extern __shared__ float4 Xraw[];
    float2* X = (float2*)Xraw;
    const int d = blockIdx.x & (DIM - 1);
    const int p = blockIdx.x >> 9;
    unsigned short* u1 = uT + (size_t)((2*p    )*DIM + d) * FFT_N;
    unsigned short* u2 = uT + (size_t)((2*p + 1)*DIM + d) * FFT_N;
    const int t = threadIdx.x;
    {
        short8v a = *(const short8v*)(u1 + 8*t);
        short8v b = *(const short8v*)(u2 + 8*t);
        float2 E[8];
        #pragma unroll
        for (int j = 0; j < 8; ++j)
            E[j] = make_float2(bf2f((unsigned short)a[j]), bf2f((unsigned short)b[j]));
        store8(X, t, E);
    }
    __syncthreads();
    dif4_stage<11>(X);
    dif4_stage<9>(X);
    dif4_stage<7>(X);
    dif4_stage<5>(X);
    dif4_stage<3>(X);
    {
        float2 E[8];
        load8(X, t, E);
        reg_fwd(E);
        const float2* F = Fbr + (size_t)d*FFT_N + 8*t;
        #pragma unroll
        for (int j = 0; j < 8; ++j) E[j] = cmulf(E[j], F[j]);
        reg_inv(E);
        store8(X, t, E);
    }
    __syncthreads();
    dit4_stage_inv<3>(X);
    dit4_stage_inv<5>(X);
    dit4_stage_inv<7>(X);
    dit4_stage_inv<9>(X);
    dit4_stage_inv<11>(X);
    {
        float2 E[8];
        load8(X, t, E);
        const float sc = 1.0f / (float)FFT_N;
        short8v a, b;
        #pragma unroll
        for (int j = 0; j < 8; ++j) {
            a[j] = (short)f2bf(E[j].x * sc);
            b[j] = (short)f2bf(E[j].y * sc);
        }
        *(short8v*)(u1 + 8*t) = a;
        *(short8v*)(u2 + 8*t) = b;
    }
}

// ------------------------------------------------- depthwise conv + transpose
__global__ void conv_transpose_kernel(const unsigned short* __restrict__ u,
                                      const float* __restrict__ conv_w,
                                      const float* __restrict__ conv_b,
                                      unsigned short* __restrict__ uT) {
    __shared__ float tile[66][65];
    const int bid = blockIdx.x;
    const int dt = bid & 7, st = (bid >> 3) & 127, b = bid >> 10;
    const int d0 = dt*64, s0 = st*64;
    const int t = threadIdx.x;
    const int rr = t >> 4, c4 = (t & 15) * 4;
    for (int r = rr; r < 66; r += 16) {
        const int s = s0 + r - 1;
        float v0=0.f, v1=0.f, v2=0.f, v3=0.f;
        if (s >= 0 && s < NS) {
            short4v xv = *(const short4v*)&u[((size_t)(b*NS + s))*DIM + d0 + c4];
            v0=bf2f((unsigned short)xv[0]); v1=bf2f((unsigned short)xv[1]);
            v2=bf2f((unsigned short)xv[2]); v3=bf2f((unsigned short)xv[3]);
        }
        tile[r][c4]=v0; tile[r][c4+1]=v1; tile[r][c4+2]=v2; tile[r][c4+3]=v3;
    }
    __syncthreads();
    const int dl = t >> 4, s4 = (t & 15) * 4;
    #pragma unroll
    for (int p = 0; p < 4; ++p) {
        const int dc = dl + p*16;
        const int d = d0 + dc;
        const float w0 = conv_w[d*3], w1 = conv_w[d*3+1], w2 = conv_w[d*3+2];
        const float cb = conv_b[d];
        short4v o;
        #pragma unroll
        for (int j = 0; j < 4; ++j) {
            const int sx = s4 + j;
            const float val = tile[sx][dc]*w0 + tile[sx+1][dc]*w1 + tile[sx+2][dc]*w2 + cb;
            o[j] = (short)f2bf(val);
        }
        *(short4v*)&uT[((size_t)(b*DIM + d))*FFT_N + s0 + s4] = o;
    }
}

// ---------------------------------------------------------------- gating
__global__ void gate_kernel(unsigned short* __restrict__ vg, const unsigned short* __restrict__ yT) {
    __shared__ float tile[64][65];
    const int bid = blockIdx.x;
    const int dt = bid & 7, st = (bid >> 3) & 127, b = bid >> 10;
    const int d0 = dt*64, s0 = st*64;
    const int t = threadIdx.x;
    const int dl = t >> 4, s4 = (t & 15) * 4;
    #pragma unroll
    for (int p = 0; p < 4; ++p) {
        const int d = dl + p*16;
        short4v y = *(const short4v*)&yT[((size_t)(b*DIM + d0 + d))*FFT_N + s0 + s4];
        tile[d][s4]  =bf2f((unsigned short)y[0]); tile[d][s4+1]=bf2f((unsigned short)y[1]);
        tile[d][s4+2]=bf2f((unsigned short)y[2]); tile[d][s4+3]=bf2f((unsigned short)y[3]);
    }
    __syncthreads();
    const int sl = t >> 4, d4 = (t & 15) * 4;
    #pragma unroll
    for (int p = 0; p < 4; ++p) {
        const int s = s0 + sl + p*16;
        unsigned short* pv = &vg[((size_t)(b*NS + s))*DIM + d0 + d4];
        short4v v = *(short4v*)pv;
        short4v o;
        #pragma unroll
        for (int j = 0; j < 4; ++j)
            o[j] = (short)f2bf(bf2f((unsigned short)v[j]) * tile[d4+j][sl + p*16]);
        *(short4v*)pv = o;
    }
}

// ---------------------------------------------------------------- bf16 GEMM
// MODE 0: Cb = bf16(val);  MODE 2: Cf = val (fp32)
template<int MODE>
__global__ __launch_bounds__(256)
void gemm_bt_kernel(const unsigned short* __restrict__ A,
                    const unsigned short* __restrict__ BT,
                    const float* __restrict__ bias,
                    float* __restrict__ Cf,
                    unsigned short* __restrict__ Cb) {
    __shared__ unsigned short As[128*32];
    __shared__ unsigned short Bs[128*32];
    const int tid = threadIdx.x;
    const int wid = tid >> 6, lane = tid & 63;
    const int m0 = blockIdx.y * 128, n0 = blockIdx.x * 128;
    const int srow = wid*16 + (lane >> 2);
    const int scol = (lane & 3) * 8;
    const unsigned short* gA = A  + (size_t)(m0 + srow)*DIM + scol;
    const unsigned short* gB = BT + (size_t)(n0 + srow)*DIM + scol;
    unsigned short* lA = As + wid*512;
    unsigned short* lB = Bs + wid*512;
    const int wr = wid >> 1, wc = wid & 1;
    const int fr = lane & 15, fq = lane >> 4;
    f32x4 acc[4][4] = {};
    for (int k0 = 0; k0 < DIM; k0 += 32) {
        __syncthreads();
        gload16(gA + k0,                  lA);
        gload16(gA + k0 + (size_t)64*DIM, lA + 2048);
        gload16(gB + k0,                  lB);
        gload16(gB + k0 + (size_t)64*DIM, lB + 2048);
        __syncthreads();
        bf16x8 af[4], bfr[4];
        #pragma unroll
        for (int mi = 0; mi < 4; ++mi)
            af[mi] = *(const bf16x8*)&As[(wr*64 + mi*16 + fr)*32 + fq*8];
        #pragma unroll
        for (int ni = 0; ni < 4; ++ni)
            bfr[ni] = *(const bf16x8*)&Bs[(wc*64 + ni*16 + fr)*32 + fq*8];
        #pragma unroll
        for (int mi = 0; mi < 4; ++mi)
            #pragma unroll
            for (int ni = 0; ni < 4; ++ni)
                acc[mi][ni] = __builtin_amdgcn_mfma_f32_16x16x32_bf16(af[mi], bfr[ni], acc[mi][ni], 0, 0, 0);
    }
    #pragma unroll
    for (int ni = 0; ni < 4; ++ni) {
        const int c = n0 + wc*64 + ni*16 + fr;
        const float bv = bias[c];
        #pragma unroll
        for (int mi = 0; mi < 4; ++mi) {
            const int rbase = m0 + wr*64 + mi*16 + fq*4;
            #pragma unroll
            for (int j = 0; j < 4; ++j) {
                const size_t idx = (size_t)(rbase + j)*DIM + c;
                const float val = acc[mi][ni][j] + bv;
                if (MODE == 0) Cb[idx] = f2bf(val);
                else           Cf[idx] = val;
            }
        }
    }
}

// -------------------------------------- fused v,z GEMM: g0 = (v+bv)*sigmoid(z+bz)
__global__ __launch_bounds__(256)
void gemm_vz_kernel(const unsigned short* __restrict__ A,
                    const unsigned short* __restrict__ BT,   // w_inT (1536,512)
                    const float* __restrict__ bias,          // b_in
                    unsigned short* __restrict__ Cb) {
    __shared__ unsigned short As[128*32];
    __shared__ unsigned short Bv[128*32];
    __shared__ unsigned short Bz[128*32];
    const int tid = threadIdx.x;
    const int wid = tid >> 6, lane = tid & 63;
    const int m0 = blockIdx.y * 128, n0 = blockIdx.x * 128;
    const int srow = wid*16 + (lane >> 2);
    const int scol = (lane & 3) * 8;
    const unsigned short* gA  = A  + (size_t)(m0 + srow)*DIM + scol;
    const unsigned short* gBv = BT + (size_t)(n0 + srow)*DIM + scol;
    const unsigned short* gBz = BT + (size_t)(1024 + n0 + srow)*DIM + scol;
    unsigned short* lA  = As + wid*512;
    unsigned short* lBv = Bv + wid*512;
    unsigned short* lBz = Bz + wid*512;
    const int wr = wid >> 1, wc = wid & 1;
    const int fr = lane & 15, fq = lane >> 4;
    f32x4 accv[4][4] = {};
    f32x4 accz[4][4] = {};
    for (int k0 = 0; k0 < DIM; k0 += 32) {
        __syncthreads();
        gload16(gA  + k0,                  lA);
        gload16(gA  + k0 + (size_t)64*DIM, lA  + 2048);
        gload16(gBv + k0,                  lBv);
        gload16(gBv + k0 + (size_t)64*DIM, lBv + 2048);
        gload16(gBz + k0,                  lBz);
        gload16(gBz + k0 + (size_t)64*DIM, lBz + 2048);
        __syncthreads();
        bf16x8 af[4], bf_[4];
        #pragma unroll
        for (int mi = 0; mi < 4; ++mi)
            af[mi] = *(const bf16x8*)&As[(wr*64 + mi*16 + fr)*32 + fq*8];
        #pragma unroll
        for (int ni = 0; ni < 4; ++ni)
            bf_[ni] = *(const bf16x8*)&Bv[(wc*64 + ni*16 + fr)*32 + fq*8];
        #pragma unroll
        for (int mi = 0; mi < 4; ++mi)
            #pragma unroll
            for (int ni = 0; ni < 4; ++ni)
                accv[mi][ni] = __builtin_amdgcn_mfma_f32_16x16x32_bf16(af[mi], bf_[ni], accv[mi][ni], 0, 0, 0);
        #pragma unroll
        for (int ni = 0; ni < 4; ++ni)
            bf_[ni] = *(const bf16x8*)&Bz[(wc*64 + ni*16 + fr)*32 + fq*8];
        #pragma unroll
        for (int mi = 0; mi < 4; ++mi)
            #pragma unroll
            for (int ni = 0; ni < 4; ++ni)
                accz[mi][ni] = __builtin_amdgcn_mfma_f32_16x16x32_bf16(af[mi], bf_[ni], accz[mi][ni], 0, 0, 0);
    }
    #pragma unroll
    for (int ni = 0; ni < 4; ++ni) {
        const int c = n0 + wc*64 + ni*16 + fr;
        const float bv = bias[c];
        const float bz = bias[1024 + c];
        #pragma unroll
        for (int mi = 0; mi < 4; ++mi) {
            const int rbase = m0 + wr*64 + mi*16 + fq*4;
            #pragma unroll
            for (int j = 0; j < 4; ++j) {
                const size_t idx = (size_t)(rbase + j)*DIM + c;
                const float vv = accv[mi][ni][j] + bv;
                const float zz = accz[mi][ni][j] + bz;
                const float sg = 1.0f / (1.0f + __expf(-zz));
                Cb[idx] = f2bf(vv * sg);
            }
        }
    }
}

// ---------------------------------------------------------------- launcher
extern "C" void kernel_launch(void* const* d_in, const int* in_sizes, int n_in,
                              void* d_out, int out_size, void* d_ws, size_t ws_size,
                              hipStream_t stream) {
    const float* x      = (const float*)d_in[0];
    const float* w1     = (const float*)d_in[1];
    const float* b1     = (const float*)d_in[2];
    const float* w2     = (const float*)d_in[3];
    const float* b2     = (const float*)d_in[4];
    const float* w3     = (const float*)d_in[5];
    const float* b3     = (const float*)d_in[6];
    const float* conv_w = (const float*)d_in[7];
    const float* conv_b = (const float*)d_in[8];
    const float* w_in   = (const float*)d_in[9];
    const float* b_in   = (const float*)d_in[10];
    const float* w_out  = (const float*)d_in[11];
    const float* b_out  = (const float*)d_in[12];
    float* out = (float*)d_out;

    const size_t NEED = 167772160ULL;              // 160 MiB (known to fit)
    if (ws_size < NEED) return;
    char* ws = (char*)d_ws;
    float2*         Fbr    = (float2*)ws;                               // 32 MiB
    unsigned short* xb     = (unsigned short*)(ws + (size_t)( 32<<20)); // 32 MiB
    unsigned short* W2     = (unsigned short*)(ws + (size_t)( 64<<20)); // u / g
    unsigned short* W3     = (unsigned short*)(ws + (size_t)( 96<<20)); // filtT / uT
    char*           W4     = ws + (size_t)(128<<20);
    float*          filt   = (float*)W4;
    float*          filtT  = (float*)(ws + (size_t)(96<<20));
    unsigned short* w_inT  = (unsigned short*)W4;                       // after filt dead
    unsigned short* w_outT = (unsigned short*)(W4 + (size_t)(2<<20));

    // 1. implicit filter MLP -> filt (S, D) fp32
    filter_mlp_kernel<<<NS, 64, 0, stream>>>(w1, b1, w2, b2, w3, b3, filt);
    // 2. transpose filt -> filtT (D, S) fp32
    transpose_f32_kernel<<<dim3(DIM/64, NS/64), 256, 0, stream>>>(filt, filtT, NS, DIM);
    // 3. filter spectrum (permuted order) -> Fbr
    fft_filt_kernel<<<DIM, FT, FFT_N*sizeof(float2), stream>>>(filtT, Fbr);
    // 4. casts
    cast_x_kernel<<<(MTOT*DIM/8)/256, 256, 0, stream>>>(x, xb);
    castT_kernel<<<dim3(1536/64, DIM/64), 256, 0, stream>>>(w_in, w_inT, DIM, 1536);
    castT_kernel<<<dim3(DIM/64, DIM/64), 256, 0, stream>>>(w_out, w_outT, DIM, DIM);
    // 5. u = x @ w_in[:,512:1024] + b -> W2 (bf16)
    gemm_bt_kernel<0><<<dim3(4, MTOT/128), 256, 0, stream>>>(xb, w_inT + 512*DIM, b_in + 512, nullptr, W2);
    // 6. depthwise conv + transpose: W2 -> W3 (B,D,S)
    conv_transpose_kernel<<<NB*(NS/64)*(DIM/64), 256, 0, stream>>>(W2, conv_w, conv_b, W3);
    // 7. packed FFT circular conv, in-place on W3 rows
    fft_conv_kernel<<<(NB/2)*DIM, FT, FFT_N*sizeof(float2), stream>>>(W3, Fbr);
    // 8. g0 = (v+bv)*sigmoid(z+bz) fused -> W2
    gemm_vz_kernel<<<dim3(4, MTOT/128), 256, 0, stream>>>(xb, w_inT, b_in, W2);
    // 9. g = g0 * y (transposed read of W3), in-place on W2
    gate_kernel<<<NB*(NS/64)*(DIM/64), 256, 0, stream>>>(W2, W3);
    // 10. out = g @ w_out + b_out -> d_out fp32
    gemm_bt_kernel<2><<<dim3(4, MTOT/128), 256, 0, stream>>>(W2, w_outT, b_out, out, nullptr);
}

// Round 6
// 259.106 us; speedup vs baseline: 4.8392x; 1.2363x over previous
//
#include <hip/hip_runtime.h>
#include <math.h>

#define DIM   512
#define NB    4
#define NS    8192
#define FFT_N 8192
#define FT    1024
#define MTOT  (NB*NS)

typedef __attribute__((ext_vector_type(8))) short bf16x8;
typedef __attribute__((ext_vector_type(4))) short short4v;
typedef __attribute__((ext_vector_type(8))) short short8v;
typedef __attribute__((ext_vector_type(4))) float f32x4;

// ---------------------------------------------------------------- helpers
__device__ __forceinline__ float bf2f(unsigned short u) {
    union { unsigned int i; float f; } v; v.i = ((unsigned int)u) << 16; return v.f;
}
__device__ __forceinline__ unsigned short f2bf(float f) {
    union { float f; unsigned int i; } v; v.f = f;
    unsigned int r = v.i + 0x7fffu + ((v.i >> 16) & 1u);
    return (unsigned short)(r >> 16);
}
__device__ __forceinline__ float2 cmulf(float2 a, float2 b) {
    return make_float2(a.x*b.x - a.y*b.y, a.x*b.y + a.y*b.x);
}
__device__ __forceinline__ float2 cadd(float2 a, float2 b) { return make_float2(a.x+b.x, a.y+b.y); }
__device__ __forceinline__ float2 csub(float2 a, float2 b) { return make_float2(a.x-b.x, a.y-b.y); }
__device__ __forceinline__ float gelu_exact(float x) {
    return 0.5f * x * (1.0f + erff(x * 0.70710678118654752f));
}
__device__ __forceinline__ void gload16(const void* g, void* l) {
    __builtin_amdgcn_global_load_lds((const __attribute__((address_space(1))) void*)g,
                                     (__attribute__((address_space(3))) void*)l, 16, 0, 0);
}

// ---------------------------------------------------------------- filter MLP
__global__ void filter_mlp_kernel(const float* __restrict__ w1, const float* __restrict__ b1,
                                  const float* __restrict__ w2, const float* __restrict__ b2,
                                  const float* __restrict__ w3, const float* __restrict__ b3,
                                  float* __restrict__ filt) {
    __shared__ float h1[64];
    __shared__ float h2[64];
    const int s = blockIdx.x;
    const int t = threadIdx.x;          // 64 threads
    const float pos = (float)s / (float)(NS - 1);
    h1[t] = gelu_exact(pos * w1[t] + b1[t]);
    __syncthreads();
    float acc = b2[t];
    #pragma unroll 8
    for (int j = 0; j < 64; ++j) acc += h1[j] * w2[j*64 + t];
    h2[t] = gelu_exact(acc);
    __syncthreads();
    for (int d = t; d < DIM; d += 64) {
        float o = b3[d];
        #pragma unroll 8
        for (int j = 0; j < 64; ++j) o += h2[j] * w3[j*DIM + d];
        filt[(size_t)s*DIM + d] = o;
    }
}

// ------------------------------------------------- fp32 transpose (R,C)->(C,R)
__global__ void transpose_f32_kernel(const float* __restrict__ in, float* __restrict__ out,
                                     int R, int C) {
    __shared__ float tile[64][65];
    const int c0 = blockIdx.x * 64, r0 = blockIdx.y * 64;
    const int t = threadIdx.x;
    const int rr = t >> 4, c4 = (t & 15) * 4;
    #pragma unroll
    for (int p = 0; p < 4; ++p) {
        const int r = rr + p*16;
        float4 v = *(const float4*)&in[(size_t)(r0 + r)*C + c0 + c4];
        tile[r][c4+0]=v.x; tile[r][c4+1]=v.y; tile[r][c4+2]=v.z; tile[r][c4+3]=v.w;
    }
    __syncthreads();
    const int cc = t >> 4, r4 = (t & 15) * 4;
    #pragma unroll
    for (int p = 0; p < 4; ++p) {
        const int c = cc + p*16;
        float4 o = make_float4(tile[r4+0][c], tile[r4+1][c], tile[r4+2][c], tile[r4+3][c]);
        *(float4*)&out[(size_t)(c0 + c)*R + r0 + r4] = o;
    }
}

// ------------------------------------------- cast+transpose (R,C)f32->(C,R)bf16
__global__ void castT_kernel(const float* __restrict__ in, unsigned short* __restrict__ outT,
                             int R, int C) {
    __shared__ float tile[64][65];
    const int c0 = blockIdx.x * 64, r0 = blockIdx.y * 64;
    const int t = threadIdx.x;
    const int rr = t >> 4, c4 = (t & 15) * 4;
    #pragma unroll
    for (int p = 0; p < 4; ++p) {
        const int r = rr + p*16;
        float4 v = *(const float4*)&in[(size_t)(r0 + r)*C + c0 + c4];
        tile[r][c4+0]=v.x; tile[r][c4+1]=v.y; tile[r][c4+2]=v.z; tile[r][c4+3]=v.w;
    }
    __syncthreads();
    const int cc = t >> 4, r4 = (t & 15) * 4;
    #pragma unroll
    for (int p = 0; p < 4; ++p) {
        const int c = cc + p*16;
        short4v o;
        o[0] = (short)f2bf(tile[r4+0][c]); o[1] = (short)f2bf(tile[r4+1][c]);
        o[2] = (short)f2bf(tile[r4+2][c]); o[3] = (short)f2bf(tile[r4+3][c]);
        *(short4v*)&outT[(size_t)(c0 + c)*R + r0 + r4] = o;
    }
}

// ---------------------------------------------------------------- cast x->bf16
__global__ void cast_x_kernel(const float* __restrict__ in, unsigned short* __restrict__ out) {
    const size_t i = ((size_t)blockIdx.x * 256 + threadIdx.x) * 8;
    float4 a = *(const float4*)&in[i];
    float4 b = *(const float4*)&in[i+4];
    short8v o;
    o[0]=(short)f2bf(a.x); o[1]=(short)f2bf(a.y); o[2]=(short)f2bf(a.z); o[3]=(short)f2bf(a.w);
    o[4]=(short)f2bf(b.x); o[5]=(short)f2bf(b.y); o[6]=(short)f2bf(b.z); o[7]=(short)f2bf(b.w);
    *(short8v*)&out[i] = o;
}

// ---------------------------------------------------------------- FFT pieces
// Radix-4 DIF forward stage: q = quarter, L = 4q, W = e^{-2pi i/L}
template<int LOGQ>
__device__ __forceinline__ void dif4_stage(float2* X) {
    const int q = 1 << LOGQ;
    const float step = -6.28318530717958647692f / (float)(4*q);
    #pragma unroll
    for (int it = 0; it < (FFT_N/4)/FT; ++it) {
        const int idx = threadIdx.x + it*FT;
        const int g = idx >> LOGQ, k = idx & (q-1);
        const int base = (g << (LOGQ+2)) + k;
        float2 a=X[base], b=X[base+q], c=X[base+2*q], d=X[base+3*q];
        float2 t0=cadd(a,c), t1=csub(a,c), t2=cadd(b,d), t3=csub(b,d);
        float2 y0=cadd(t0,t2), y2=csub(t0,t2);
        float2 y1=make_float2(t1.x+t3.y, t1.y-t3.x);   // t1 - i*t3
        float2 y3=make_float2(t1.x-t3.y, t1.y+t3.x);   // t1 + i*t3
        float sv, cv; __sincosf(step*(float)k, &sv, &cv);
        float2 w1=make_float2(cv, sv);
        float2 w2=cmulf(w1, w1);
        float2 w3=cmulf(w2, w1);
        X[base]     = y0;
        X[base+q]   = cmulf(y1, w1);
        X[base+2*q] = cmulf(y2, w2);
        X[base+3*q] = cmulf(y3, w3);
    }
    __syncthreads();
}

// Radix-4 DIT inverse stage (conjugate twiddles), exact inverse of dif4_stage
template<int LOGQ>
__device__ __forceinline__ void dit4_stage_inv(float2* X) {
    const int q = 1 << LOGQ;
    const float step = 6.28318530717958647692f / (float)(4*q);
    #pragma unroll
    for (int it = 0; it < (FFT_N/4)/FT; ++it) {
        const int idx = threadIdx.x + it*FT;
        const int g = idx >> LOGQ, k = idx & (q-1);
        const int base = (g << (LOGQ+2)) + k;
        float sv, cv; __sincosf(step*(float)k, &sv, &cv);
        float2 w1=make_float2(cv, sv);
        float2 w2=cmulf(w1, w1);
        float2 w3=cmulf(w2, w1);
        float2 u0=X[base];
        float2 u1=cmulf(X[base+q],   w1);
        float2 u2=cmulf(X[base+2*q], w2);
        float2 u3=cmulf(X[base+3*q], w3);
        float2 s02=cadd(u0,u2), d02=csub(u0,u2);
        float2 s13=cadd(u1,u3), d13=csub(u1,u3);
        X[base]     = cadd(s02, s13);
        X[base+2*q] = csub(s02, s13);
        X[base+q]   = make_float2(d02.x - d13.y, d02.y + d13.x);   // d02 + i*d13
        X[base+3*q] = make_float2(d02.x + d13.y, d02.y - d13.x);   // d02 - i*d13
    }
    __syncthreads();
}

// Register tail: size-8 DFT on 8 contiguous elements (radix-4 q=2 + radix-2)
__device__ __forceinline__ void reg_fwd(float2* E) {
    const float C = 0.70710678118654752f;
    {   // k=0: elems 0,2,4,6, twiddles = 1
        float2 t0=cadd(E[0],E[4]), t1=csub(E[0],E[4]);
        float2 t2=cadd(E[2],E[6]), t3=csub(E[2],E[6]);
        E[0]=cadd(t0,t2);
        E[4]=csub(t0,t2);
        E[2]=make_float2(t1.x+t3.y, t1.y-t3.x);
        E[6]=make_float2(t1.x-t3.y, t1.y+t3.x);
    }
    {   // k=1: elems 1,3,5,7; w1=(C,-C), w2=(0,-1), w3=(-C,-C)
        float2 t0=cadd(E[1],E[5]), t1=csub(E[1],E[5]);
        float2 t2=cadd(E[3],E[7]), t3=csub(E[3],E[7]);
        float2 y0=cadd(t0,t2), y2=csub(t0,t2);
        float2 y1=make_float2(t1.x+t3.y, t1.y-t3.x);
        float2 y3=make_float2(t1.x-t3.y, t1.y+t3.x);
        E[1]=y0;
        E[3]=make_float2(C*(y1.x+y1.y),  C*(y1.y-y1.x));   // y1*(C,-C)
        E[5]=make_float2(y2.y, -y2.x);                      // -i*y2
        E[7]=make_float2(C*(y3.y-y3.x), -C*(y3.x+y3.y));    // y3*(-C,-C)
    }
    #pragma unroll
    for (int j = 0; j < 8; j += 2) {
        float2 a=E[j], b=E[j+1];
        E[j]=cadd(a,b); E[j+1]=csub(a,b);
    }
}
__device__ __forceinline__ void reg_inv(float2* E) {
    const float C = 0.70710678118654752f;
    #pragma unroll
    for (int j = 0; j < 8; j += 2) {
        float2 a=E[j], b=E[j+1];
        E[j]=cadd(a,b); E[j+1]=csub(a,b);
    }
    {   // k=0
        float2 u0=E[0], u1=E[2], u2=E[4], u3=E[6];
        float2 s02=cadd(u0,u2), d02=csub(u0,u2);
        float2 s13=cadd(u1,u3), d13=csub(u1,u3);
        E[0]=cadd(s02,s13);
        E[4]=csub(s02,s13);
        E[2]=make_float2(d02.x - d13.y, d02.y + d13.x);
        E[6]=make_float2(d02.x + d13.y, d02.y - d13.x);
    }
    {   // k=1: conj twiddles (C,C), (0,1), (-C,C)
        float2 z1=E[3], z2=E[5], z3=E[7];
        float2 u0=E[1];
        float2 u1=make_float2(C*(z1.x - z1.y), C*(z1.x + z1.y));
        float2 u2=make_float2(-z2.y, z2.x);
        float2 u3=make_float2(-C*(z3.x + z3.y), C*(z3.x - z3.y));
        float2 s02=cadd(u0,u2), d02=csub(u0,u2);
        float2 s13=cadd(u1,u3), d13=csub(u1,u3);
        E[1]=cadd(s02,s13);
        E[5]=csub(s02,s13);
        E[3]=make_float2(d02.x - d13.y, d02.y + d13.x);
        E[7]=make_float2(d02.x + d13.y, d02.y - d13.x);
    }
}

__device__ __forceinline__ void load8(const float2* X, int t, float2* E) {
    const float4* b = (const float4*)(X + 8*t);
    #pragma unroll
    for (int p = 0; p < 4; ++p) {
        float4 v = b[p];
        E[2*p]   = make_float2(v.x, v.y);
        E[2*p+1] = make_float2(v.z, v.w);
    }
}
__device__ __forceinline__ void store8(float2* X, int t, const float2* E) {
    float4* b = (float4*)(X + 8*t);
    #pragma unroll
    for (int p = 0; p < 4; ++p)
        b[p] = make_float4(E[2*p].x, E[2*p].y, E[2*p+1].x, E[2*p+1].y);
}

// filter spectrum (permuted order P); filtT (D, S) fp32 rows
__global__ __launch_bounds__(FT)
void fft_filt_kernel(const float* __restrict__ filtT, float2* __restrict__ Fbr) {
    extern __shared__ float4 Xraw[];
    float2* X = (float2*)Xraw;
    const int dd = blockIdx.x;
    const int t = threadIdx.x;
    const float* f = filtT + (size_t)dd * FFT_N;
    {
        float4 a = *(const float4*)(f + 8*t);
        float4 b = *(const float4*)(f + 8*t + 4);
        float2 E[8];
        E[0]=make_float2(a.x,0.f); E[1]=make_float2(a.y,0.f);
        E[2]=make_float2(a.z,0.f); E[3]=make_float2(a.w,0.f);
        E[4]=make_float2(b.x,0.f); E[5]=make_float2(b.y,0.f);
        E[6]=make_float2(b.z,0.f); E[7]=make_float2(b.w,0.f);
        store8(X, t, E);
    }
    __syncthreads();
    dif4_stage<11>(X);
    dif4_stage<9>(X);
    dif4_stage<7>(X);
    dif4_stage<5>(X);
    dif4_stage<3>(X);
    {
        float2 E[8];
        load8(X, t, E);
        reg_fwd(E);
        float2* o = Fbr + (size_t)dd*FFT_N + 8*t;
        #pragma unroll
        for (int j = 0; j < 8; ++j) o[j] = E[j];
    }
}

// packed-pair circular conv, in-place bf16: rows (2p,d) and (2p+1,d) of uT
__global__ __launch_bounds__(FT)
void fft_conv_kernel(unsigned short* __restrict__ uT, const float2* __restrict__ Fbr) {
    extern __shared__ float4 Xraw[];
    float2* X = (float2*)Xraw;
    const int d = blockIdx.x & (DIM - 1);
    const int p = blockIdx.x >> 9;
    unsigned short* u1 = uT + (size_t)((2*p    )*DIM + d) * FFT_N;
    unsigned short* u2 = uT + (size_t)((2*p + 1)*DIM + d) * FFT_N;
    const int t = threadIdx.x;
    {
        short8v a = *(const short8v*)(u1 + 8*t);
        short8v b = *(const short8v*)(u2 + 8*t);
        float2 E[8];
        #pragma unroll
        for (int j = 0; j < 8; ++j)
            E[j] = make_float2(bf2f((unsigned short)a[j]), bf2f((unsigned short)b[j]));
        store8(X, t, E);
    }
    __syncthreads();
    dif4_stage<11>(X);
    dif4_stage<9>(X);
    dif4_stage<7>(X);
    dif4_stage<5>(X);
    dif4_stage<3>(X);
    {
        float2 E[8];
        load8(X, t, E);
        reg_fwd(E);
        const float2* F = Fbr + (size_t)d*FFT_N + 8*t;
        #pragma unroll
        for (int j = 0; j < 8; ++j) E[j] = cmulf(E[j], F[j]);
        reg_inv(E);
        store8(X, t, E);
    }
    __syncthreads();
    dit4_stage_inv<3>(X);
    dit4_stage_inv<5>(X);
    dit4_stage_inv<7>(X);
    dit4_stage_inv<9>(X);
    dit4_stage_inv<11>(X);
    {
        float2 E[8];
        load8(X, t, E);
        const float sc = 1.0f / (float)FFT_N;
        short8v a, b;
        #pragma unroll
        for (int j = 0; j < 8; ++j) {
            a[j] = (short)f2bf(E[j].x * sc);
            b[j] = (short)f2bf(E[j].y * sc);
        }
        *(short8v*)(u1 + 8*t) = a;
        *(short8v*)(u2 + 8*t) = b;
    }
}

// ------------------------------------------------- depthwise conv + transpose
__global__ void conv_transpose_kernel(const unsigned short* __restrict__ u,
                                      const float* __restrict__ conv_w,
                                      const float* __restrict__ conv_b,
                                      unsigned short* __restrict__ uT) {
    __shared__ float tile[66][65];
    const int bid = blockIdx.x;
    const int dt = bid & 7, st = (bid >> 3) & 127, b = bid >> 10;
    const int d0 = dt*64, s0 = st*64;
    const int t = threadIdx.x;
    const int rr = t >> 4, c4 = (t & 15) * 4;
    for (int r = rr; r < 66; r += 16) {
        const int s = s0 + r - 1;
        float v0=0.f, v1=0.f, v2=0.f, v3=0.f;
        if (s >= 0 && s < NS) {
            short4v xv = *(const short4v*)&u[((size_t)(b*NS + s))*DIM + d0 + c4];
            v0=bf2f((unsigned short)xv[0]); v1=bf2f((unsigned short)xv[1]);
            v2=bf2f((unsigned short)xv[2]); v3=bf2f((unsigned short)xv[3]);
        }
        tile[r][c4]=v0; tile[r][c4+1]=v1; tile[r][c4+2]=v2; tile[r][c4+3]=v3;
    }
    __syncthreads();
    const int dl = t >> 4, s4 = (t & 15) * 4;
    #pragma unroll
    for (int p = 0; p < 4; ++p) {
        const int dc = dl + p*16;
        const int d = d0 + dc;
        const float w0 = conv_w[d*3], w1 = conv_w[d*3+1], w2 = conv_w[d*3+2];
        const float cb = conv_b[d];
        short4v o;
        #pragma unroll
        for (int j = 0; j < 4; ++j) {
            const int sx = s4 + j;
            const float val = tile[sx][dc]*w0 + tile[sx+1][dc]*w1 + tile[sx+2][dc]*w2 + cb;
            o[j] = (short)f2bf(val);
        }
        *(short4v*)&uT[((size_t)(b*DIM + d))*FFT_N + s0 + s4] = o;
    }
}

// ---------------------------------------------------------------- gating
__global__ void gate_kernel(unsigned short* __restrict__ vg, const unsigned short* __restrict__ yT) {
    __shared__ float tile[64][65];
    const int bid = blockIdx.x;
    const int dt = bid & 7, st = (bid >> 3) & 127, b = bid >> 10;
    const int d0 = dt*64, s0 = st*64;
    const int t = threadIdx.x;
    const int dl = t >> 4, s4 = (t & 15) * 4;
    #pragma unroll
    for (int p = 0; p < 4; ++p) {
        const int d = dl + p*16;
        short4v y = *(const short4v*)&yT[((size_t)(b*DIM + d0 + d))*FFT_N + s0 + s4];
        tile[d][s4]  =bf2f((unsigned short)y[0]); tile[d][s4+1]=bf2f((unsigned short)y[1]);
        tile[d][s4+2]=bf2f((unsigned short)y[2]); tile[d][s4+3]=bf2f((unsigned short)y[3]);
    }
    __syncthreads();
    const int sl = t >> 4, d4 = (t & 15) * 4;
    #pragma unroll
    for (int p = 0; p < 4; ++p) {
        const int s = s0 + sl + p*16;
        unsigned short* pv = &vg[((size_t)(b*NS + s))*DIM + d0 + d4];
        short4v v = *(short4v*)pv;
        short4v o;
        #pragma unroll
        for (int j = 0; j < 4; ++j)
            o[j] = (short)f2bf(bf2f((unsigned short)v[j]) * tile[d4+j][sl + p*16]);
        *(short4v*)pv = o;
    }
}

// ---------------------------------------------------------------- bf16 GEMM
// Double-buffered pipeline + XCD swizzle. Grid must be dim3(4, 256).
// MODE 0: Cb = bf16(val);  MODE 2: Cf = val (fp32)
template<int MODE>
__global__ __launch_bounds__(256)
void gemm_bt_kernel(const unsigned short* __restrict__ A,
                    const unsigned short* __restrict__ BT,
                    const float* __restrict__ bias,
                    float* __restrict__ Cf,
                    unsigned short* __restrict__ Cb) {
    __shared__ unsigned short As[2][4096];
    __shared__ unsigned short Bs[2][4096];
    const int tid = threadIdx.x;
    const int wid = tid >> 6, lane = tid & 63;
    // XCD swizzle: 1024 blocks, 8 XCDs, 128 per XCD; same-m0 col-blocks adjacent
    const int bid = blockIdx.y * 4 + blockIdx.x;
    const int swz = (bid & 7) * 128 + (bid >> 3);
    const int m0 = (swz >> 2) * 128, n0 = (swz & 3) * 128;
    const int srow = wid*16 + (lane >> 2);
    const int scol = (lane & 3) * 8;
    const unsigned short* gA = A  + (size_t)(m0 + srow)*DIM + scol;
    const unsigned short* gB = BT + (size_t)(n0 + srow)*DIM + scol;
    const int wr = wid >> 1, wc = wid & 1;
    const int fr = lane & 15, fq = lane >> 4;
    f32x4 acc[4][4] = {};
    // prologue: stage k=0 into buf 0
    gload16(gA,                  &As[0][wid*512]);
    gload16(gA + (size_t)64*DIM, &As[0][wid*512 + 2048]);
    gload16(gB,                  &Bs[0][wid*512]);
    gload16(gB + (size_t)64*DIM, &Bs[0][wid*512 + 2048]);
    int cur = 0;
    for (int k0 = 0; k0 < DIM; k0 += 32) {
        __syncthreads();                      // buf[cur] ready (vmcnt+lgkm drained)
        if (k0 + 32 < DIM) {                  // prefetch next tile into buf[cur^1]
            const int nx = cur ^ 1;
            gload16(gA + k0 + 32,                  &As[nx][wid*512]);
            gload16(gA + k0 + 32 + (size_t)64*DIM, &As[nx][wid*512 + 2048]);
            gload16(gB + k0 + 32,                  &Bs[nx][wid*512]);
            gload16(gB + k0 + 32 + (size_t)64*DIM, &Bs[nx][wid*512 + 2048]);
        }
        bf16x8 af[4], bfr[4];
        #pragma unroll
        for (int mi = 0; mi < 4; ++mi)
            af[mi] = *(const bf16x8*)&As[cur][(wr*64 + mi*16 + fr)*32 + fq*8];
        #pragma unroll
        for (int ni = 0; ni < 4; ++ni)
            bfr[ni] = *(const bf16x8*)&Bs[cur][(wc*64 + ni*16 + fr)*32 + fq*8];
        #pragma unroll
        for (int mi = 0; mi < 4; ++mi)
            #pragma unroll
            for (int ni = 0; ni < 4; ++ni)
                acc[mi][ni] = __builtin_amdgcn_mfma_f32_16x16x32_bf16(af[mi], bfr[ni], acc[mi][ni], 0, 0, 0);
        cur ^= 1;
    }
    #pragma unroll
    for (int ni = 0; ni < 4; ++ni) {
        const int c = n0 + wc*64 + ni*16 + fr;
        const float bv = bias[c];
        #pragma unroll
        for (int mi = 0; mi < 4; ++mi) {
            const int rbase = m0 + wr*64 + mi*16 + fq*4;
            #pragma unroll
            for (int j = 0; j < 4; ++j) {
                const size_t idx = (size_t)(rbase + j)*DIM + c;
                const float val = acc[mi][ni][j] + bv;
                if (MODE == 0) Cb[idx] = f2bf(val);
                else           Cf[idx] = val;
            }
        }
    }
}

// -------------------------------------- fused v,z GEMM: g0 = (v+bv)*sigmoid(z+bz)
__global__ __launch_bounds__(256)
void gemm_vz_kernel(const unsigned short* __restrict__ A,
                    const unsigned short* __restrict__ BT,   // w_inT (1536,512)
                    const float* __restrict__ bias,          // b_in
                    unsigned short* __restrict__ Cb) {
    __shared__ unsigned short As[2][4096];
    __shared__ unsigned short Bv[2][4096];
    __shared__ unsigned short Bz[2][4096];
    const int tid = threadIdx.x;
    const int wid = tid >> 6, lane = tid & 63;
    const int bid = blockIdx.y * 4 + blockIdx.x;
    const int swz = (bid & 7) * 128 + (bid >> 3);
    const int m0 = (swz >> 2) * 128, n0 = (swz & 3) * 128;
    const int srow = wid*16 + (lane >> 2);
    const int scol = (lane & 3) * 8;
    const unsigned short* gA  = A  + (size_t)(m0 + srow)*DIM + scol;
    const unsigned short* gBv = BT + (size_t)(n0 + srow)*DIM + scol;
    const unsigned short* gBz = BT + (size_t)(1024 + n0 + srow)*DIM + scol;
    const int wr = wid >> 1, wc = wid & 1;
    const int fr = lane & 15, fq = lane >> 4;
    f32x4 accv[4][4] = {};
    f32x4 accz[4][4] = {};
    // prologue: stage k=0
    gload16(gA,                   &As[0][wid*512]);
    gload16(gA  + (size_t)64*DIM, &As[0][wid*512 + 2048]);
    gload16(gBv,                  &Bv[0][wid*512]);
    gload16(gBv + (size_t)64*DIM, &Bv[0][wid*512 + 2048]);
    gload16(gBz,                  &Bz[0][wid*512]);
    gload16(gBz + (size_t)64*DIM, &Bz[0][wid*512 + 2048]);
    int cur = 0;
    for (int k0 = 0; k0 < DIM; k0 += 32) {
        __syncthreads();
        if (k0 + 32 < DIM) {
            const int nx = cur ^ 1;
            gload16(gA  + k0 + 32,                  &As[nx][wid*512]);
            gload16(gA  + k0 + 32 + (size_t)64*DIM, &As[nx][wid*512 + 2048]);
            gload16(gBv + k0 + 32,                  &Bv[nx][wid*512]);
            gload16(gBv + k0 + 32 + (size_t)64*DIM, &Bv[nx][wid*512 + 2048]);
            gload16(gBz + k0 + 32,                  &Bz[nx][wid*512]);
            gload16(gBz + k0 + 32 + (size_t)64*DIM, &Bz[nx][wid*512 + 2048]);
        }
        bf16x8 af[4], bf_[4];
        #pragma unroll
        for (int mi = 0; mi < 4; ++mi)
            af[mi] = *(const bf16x8*)&As[cur][(wr*64 + mi*16 + fr)*32 + fq*8];
        #pragma unroll
        for (int ni = 0; ni < 4; ++ni)
            bf_[ni] = *(const bf16x8*)&Bv[cur][(wc*64 + ni*16 + fr)*32 + fq*8];
        #pragma unroll
        for (int mi = 0; mi < 4; ++mi)
            #pragma unroll
            for (int ni = 0; ni < 4; ++ni)
                accv[mi][ni] = __builtin_amdgcn_mfma_f32_16x16x32_bf16(af[mi], bf_[ni], accv[mi][ni], 0, 0, 0);
        #pragma unroll
        for (int ni = 0; ni < 4; ++ni)
            bf_[ni] = *(const bf16x8*)&Bz[cur][(wc*64 + ni*16 + fr)*32 + fq*8];
        #pragma unroll
        for (int mi = 0; mi < 4; ++mi)
            #pragma unroll
            for (int ni = 0; ni < 4; ++ni)
                accz[mi][ni] = __builtin_amdgcn_mfma_f32_16x16x32_bf16(af[mi], bf_[ni], accz[mi][ni], 0, 0, 0);
        cur ^= 1;
    }
    #pragma unroll
    for (int ni = 0; ni < 4; ++ni) {
        const int c = n0 + wc*64 + ni*16 + fr;
        const float bv = bias[c];
        const float bz = bias[1024 + c];
        #pragma unroll
        for (int mi = 0; mi < 4; ++mi) {
            const int rbase = m0 + wr*64 + mi*16 + fq*4;
            #pragma unroll
            for (int j = 0; j < 4; ++j) {
                const size_t idx = (size_t)(rbase + j)*DIM + c;
                const float vv = accv[mi][ni][j] + bv;
                const float zz = accz[mi][ni][j] + bz;
                const float sg = 1.0f / (1.0f + __expf(-zz));
                Cb[idx] = f2bf(vv * sg);
            }
        }
    }
}

// ---------------------------------------------------------------- launcher
extern "C" void kernel_launch(void* const* d_in, const int* in_sizes, int n_in,
                              void* d_out, int out_size, void* d_ws, size_t ws_size,
                              hipStream_t stream) {
    const float* x      = (const float*)d_in[0];
    const float* w1     = (const float*)d_in[1];
    const float* b1     = (const float*)d_in[2];
    const float* w2     = (const float*)d_in[3];
    const float* b2     = (const float*)d_in[4];
    const float* w3     = (const float*)d_in[5];
    const float* b3     = (const float*)d_in[6];
    const float* conv_w = (const float*)d_in[7];
    const float* conv_b = (const float*)d_in[8];
    const float* w_in   = (const float*)d_in[9];
    const float* b_in   = (const float*)d_in[10];
    const float* w_out  = (const float*)d_in[11];
    const float* b_out  = (const float*)d_in[12];
    float* out = (float*)d_out;

    const size_t NEED = 167772160ULL;              // 160 MiB (known to fit)
    if (ws_size < NEED) return;
    char* ws = (char*)d_ws;
    float2*         Fbr    = (float2*)ws;                               // 32 MiB
    unsigned short* xb     = (unsigned short*)(ws + (size_t)( 32<<20)); // 32 MiB
    unsigned short* W2     = (unsigned short*)(ws + (size_t)( 64<<20)); // u / g
    unsigned short* W3     = (unsigned short*)(ws + (size_t)( 96<<20)); // filtT / uT
    char*           W4     = ws + (size_t)(128<<20);
    float*          filt   = (float*)W4;
    float*          filtT  = (float*)(ws + (size_t)(96<<20));
    unsigned short* w_inT  = (unsigned short*)W4;                       // after filt dead
    unsigned short* w_outT = (unsigned short*)(W4 + (size_t)(2<<20));

    // 1. implicit filter MLP -> filt (S, D) fp32
    filter_mlp_kernel<<<NS, 64, 0, stream>>>(w1, b1, w2, b2, w3, b3, filt);
    // 2. transpose filt -> filtT (D, S) fp32
    transpose_f32_kernel<<<dim3(DIM/64, NS/64), 256, 0, stream>>>(filt, filtT, NS, DIM);
    // 3. filter spectrum (permuted order) -> Fbr
    fft_filt_kernel<<<DIM, FT, FFT_N*sizeof(float2), stream>>>(filtT, Fbr);
    // 4. casts
    cast_x_kernel<<<(MTOT*DIM/8)/256, 256, 0, stream>>>(x, xb);
    castT_kernel<<<dim3(1536/64, DIM/64), 256, 0, stream>>>(w_in, w_inT, DIM, 1536);
    castT_kernel<<<dim3(DIM/64, DIM/64), 256, 0, stream>>>(w_out, w_outT, DIM, DIM);
    // 5. u = x @ w_in[:,512:1024] + b -> W2 (bf16)
    gemm_bt_kernel<0><<<dim3(4, MTOT/128), 256, 0, stream>>>(xb, w_inT + 512*DIM, b_in + 512, nullptr, W2);
    // 6. depthwise conv + transpose: W2 -> W3 (B,D,S)
    conv_transpose_kernel<<<NB*(NS/64)*(DIM/64), 256, 0, stream>>>(W2, conv_w, conv_b, W3);
    // 7. packed FFT circular conv, in-place on W3 rows
    fft_conv_kernel<<<(NB/2)*DIM, FT, FFT_N*sizeof(float2), stream>>>(W3, Fbr);
    // 8. g0 = (v+bv)*sigmoid(z+bz) fused -> W2
    gemm_vz_kernel<<<dim3(4, MTOT/128), 256, 0, stream>>>(xb, w_inT, b_in, W2);
    // 9. g = g0 * y (transposed read of W3), in-place on W2
    gate_kernel<<<NB*(NS/64)*(DIM/64), 256, 0, stream>>>(W2, W3);
    // 10. out = g @ w_out + b_out -> d_out fp32
    gemm_bt_kernel<2><<<dim3(4, MTOT/128), 256, 0, stream>>>(W2, w_outT, b_out, out, nullptr);
}